// Round 14
// baseline (352.309 us; speedup 1.0000x reference)
//
#include <hip/hip_runtime.h>
#include <hip/hip_bf16.h>

// Problem constants
#define B_   4
#define C_   256
#define N_   3136
#define QT_  196     // N/16 q-tiles per batch
#define NKV_ 98      // N/32 kv tiles
#define CH_  4       // KV chunks (8-wave blocks: 13 qblk x 16 = 208 blocks, 1/CU)

typedef __attribute__((ext_vector_type(8)))  short bf16x8;
typedef __attribute__((ext_vector_type(4)))  float f32x4;
typedef __attribute__((ext_vector_type(16))) float f32x16;

#define LOG2E  1.4426950408889634f
#define SCALE2 (LOG2E / 16.0f)     // (1/sqrt(C)) * log2(e)
#define FMAX_  20.0f               // fixed softmax max (log2 domain); logits*log2e < ~12.3

__device__ __forceinline__ unsigned short bfbits(float f) {
  __hip_bfloat16 h = __float2bfloat16(f);
  return *(unsigned short*)&h;
}
__device__ __forceinline__ unsigned cvtpk(float lo, float hi) {
  unsigned r;
  asm("v_cvt_pk_bf16_f32 %0, %1, %2" : "=v"(r) : "v"(lo), "v"(hi));
  return r;
}

// ---- async global->LDS 16B helper (dest must be linear: base + lane*16) ----
__device__ __forceinline__ void gld16(const void* g, void* l) {
  __builtin_amdgcn_global_load_lds(
      (const __attribute__((address_space(1))) unsigned int*)g,
      (__attribute__((address_space(3))) unsigned int*)l, 16, 0, 0);
}

// key-column permutation inside each 32-group (PV zero-exchange layout)
__device__ __forceinline__ int vperm(int n) {
  int k = n & 31;
  return (n & ~31) | (k & 16) | (((k >> 2) & 1) << 3) | (k & 3) | (((k >> 3) & 1) << 2);
}

// ---- all 4 feats: [b][c][n] f32 -> [b][n][c] bf16; feat0 also copied to out slot 0 ----
__global__ __launch_bounds__(256) void transpose4_kernel(
    const float* __restrict__ f0, const float* __restrict__ f1,
    const float* __restrict__ f2, const float* __restrict__ f3,
    __hip_bfloat16* __restrict__ d0, __hip_bfloat16* __restrict__ d1,
    __hip_bfloat16* __restrict__ d2, __hip_bfloat16* __restrict__ d3,
    float* __restrict__ out) {
  __shared__ float tile[32][33];
  const int z  = blockIdx.z;
  const int fi = z >> 2;
  const int b  = z & 3;
  const float* src = (fi == 0) ? f0 : (fi == 1) ? f1 : (fi == 2) ? f2 : f3;
  __hip_bfloat16* dst = (fi == 0) ? d0 : (fi == 1) ? d1 : (fi == 2) ? d2 : d3;
  const int n0 = blockIdx.x * 32;
  const int c0 = blockIdx.y * 32;
  const int tx = threadIdx.x & 31;
  const int ty = threadIdx.x >> 5;
  const float* s = src + (size_t)b * C_ * N_;
  float* ob = out + (size_t)b * 4 * C_ * N_;
#pragma unroll
  for (int i = 0; i < 4; ++i) {
    int c = c0 + ty + i * 8;
    float v = s[(size_t)c * N_ + n0 + tx];
    tile[ty + i * 8][tx] = v;
    if (fi == 0) ob[(size_t)c * N_ + n0 + tx] = v;
  }
  __syncthreads();
  __hip_bfloat16* d = dst + (size_t)b * N_ * C_;
#pragma unroll
  for (int i = 0; i < 4; ++i) {
    int n = n0 + ty + i * 8;
    d[(size_t)n * C_ + c0 + tx] = __float2bfloat16(tile[tx][ty + i * 8]);
  }
}

// ---- converts ----
// Wv/Wl -> MFMA-fragment-linear bf16: W[ct][kk][lane(g*16+qt)][8 elems]
// mask -> coalesced per-wave-tile bf16 layout:
//   maskb[qu][kt][cl][hi][s] = mask[qu*32+cl][kt*32 + (s&3)+8*(s>>2)+4*hi] * LOG2E
__global__ __launch_bounds__(256) void cvt_all_kernel(
    const float* __restrict__ Wv, const float* __restrict__ Wl,
    const float* __restrict__ mask,
    __hip_bfloat16* __restrict__ Wvb, __hip_bfloat16* __restrict__ Wlb,
    __hip_bfloat16* __restrict__ maskb) {
  int i = blockIdx.x * 256 + threadIdx.x;
  if (i < 24576) {
    const float* src; __hip_bfloat16* dstp; int off, dst8;
    if (i < 8192) {
      off = i; src = Wv; dstp = Wvb;
      int row = off >> 5, c8 = off & 31;            // K=256: 32 groups/row
      int ct = row >> 4, qt = row & 15, kk = c8 >> 2, g = c8 & 3;
      dst8 = (ct * 8 + kk) * 64 + g * 16 + qt;
    } else {
      off = i - 8192; src = Wl; dstp = Wlb;
      int row = off >> 6, c8 = off & 63;            // K=512: 64 groups/row
      int ct = row >> 4, qt = row & 15, kk = c8 >> 2, g = c8 & 3;
      dst8 = (ct * 16 + kk) * 64 + g * 16 + qt;
    }
    const float4* s4 = (const float4*)src;
    float4 a = s4[2 * off], b = s4[2 * off + 1];
    union { unsigned short u[8]; bf16x8 v; } p;
    p.u[0]=bfbits(a.x); p.u[1]=bfbits(a.y); p.u[2]=bfbits(a.z); p.u[3]=bfbits(a.w);
    p.u[4]=bfbits(b.x); p.u[5]=bfbits(b.y); p.u[6]=bfbits(b.z); p.u[7]=bfbits(b.w);
    *(bf16x8*)(dstp + 8 * dst8) = p.v;
    return;
  }
  int j = i - 24576;
  if (j >= NKV_ * NKV_ * 32 * 2) return;   // 98*98*32*2
  const int hi  = j & 1;
  const int cl  = (j >> 1) & 31;
  const int rem = j >> 6;          // qu*98 + kt
  const int kt  = rem % NKV_;
  const int qu  = rem / NKV_;
  const int q   = qu * 32 + cl;
  const float* s = mask + (size_t)q * N_ + kt * 32 + 4 * hi;
  float4 a0 = *(const float4*)(s);
  float4 a1 = *(const float4*)(s + 8);
  float4 a2 = *(const float4*)(s + 16);
  float4 a3 = *(const float4*)(s + 24);
  union { unsigned short u[16]; bf16x8 v[2]; } p;
  p.u[0]=bfbits(a0.x*LOG2E); p.u[1]=bfbits(a0.y*LOG2E); p.u[2]=bfbits(a0.z*LOG2E); p.u[3]=bfbits(a0.w*LOG2E);
  p.u[4]=bfbits(a1.x*LOG2E); p.u[5]=bfbits(a1.y*LOG2E); p.u[6]=bfbits(a1.z*LOG2E); p.u[7]=bfbits(a1.w*LOG2E);
  p.u[8]=bfbits(a2.x*LOG2E); p.u[9]=bfbits(a2.y*LOG2E); p.u[10]=bfbits(a2.z*LOG2E); p.u[11]=bfbits(a2.w*LOG2E);
  p.u[12]=bfbits(a3.x*LOG2E); p.u[13]=bfbits(a3.y*LOG2E); p.u[14]=bfbits(a3.z*LOG2E); p.u[15]=bfbits(a3.w*LOG2E);
  __hip_bfloat16* d = maskb + ((size_t)rem * 32 + cl) * 32 + hi * 16;
  *(bf16x8*)(d)     = p.v[0];
  *(bf16x8*)(d + 8) = p.v[1];
}

// ---- vT_s[b][c][nperm] = Wv @ f_s^T + bv, all 3 stages in one launch ----
__global__ __launch_bounds__(256) void v_linear_kernel(
    const __hip_bfloat16* __restrict__ f1, const __hip_bfloat16* __restrict__ f2,
    const __hip_bfloat16* __restrict__ f3,
    const __hip_bfloat16* __restrict__ Wv,   // fragment-linear
    const float* __restrict__ bv,
    __hip_bfloat16* __restrict__ vT0, __hip_bfloat16* __restrict__ vT1,
    __hip_bfloat16* __restrict__ vT2)
{
  const int s    = blockIdx.z;
  const int b    = blockIdx.y;
  const int nblk = blockIdx.x;
  const __hip_bfloat16* fb = (s == 0) ? f1 : (s == 1) ? f2 : f3;
  __hip_bfloat16* vT = (s == 0) ? vT0 : (s == 1) ? vT1 : vT2;
  const int wave = threadIdx.x >> 6;
  const int lane = threadIdx.x & 63;
  const int qt = lane & 15, g = lane >> 4;
  const int n0 = nblk * 64;
  const __hip_bfloat16* fbb = fb + (size_t)b * N_ * C_;
  const int c0 = wave * 64;
  f32x4 acc[4][4];
#pragma unroll
  for (int u = 0; u < 4; ++u)
#pragma unroll
    for (int j = 0; j < 4; ++j) acc[u][j] = (f32x4){0.f, 0.f, 0.f, 0.f};
#pragma unroll
  for (int kk = 0; kk < 8; ++kk) {
    int ko = kk * 32 + g * 8;
    bf16x8 bb[4];
#pragma unroll
    for (int j = 0; j < 4; ++j)
      bb[j] = *(const bf16x8*)(fbb + (size_t)(n0 + j * 16 + qt) * C_ + ko);
#pragma unroll
    for (int u = 0; u < 4; ++u) {
      bf16x8 a = *(const bf16x8*)(Wv + (size_t)(((wave * 4 + u) * 8 + kk) * 64 + lane) * 8);
#pragma unroll
      for (int j = 0; j < 4; ++j)
        acc[u][j] = __builtin_amdgcn_mfma_f32_16x16x32_bf16(a, bb[j], acc[u][j], 0, 0, 0);
    }
  }
  __hip_bfloat16* outp = vT + (size_t)b * C_ * N_;
#pragma unroll
  for (int u = 0; u < 4; ++u)
#pragma unroll
    for (int j = 0; j < 4; ++j)
#pragma unroll
      for (int r = 0; r < 4; ++r) {
        int c = c0 + u * 16 + 4 * g + r;
        int n = vperm(n0 + j * 16 + qt);
        outp[(size_t)c * N_ + n] = __float2bfloat16(acc[u][j][r] + bv[c]);
      }
}

// ---- flash attention: 8 waves x 32 q-rows (512 thr), 1 block/CU, dbuf K+V ----
__global__ __launch_bounds__(512, 2) void attn_kernel(
    const __hip_bfloat16* __restrict__ qb,   // [B][N][C]
    const __hip_bfloat16* __restrict__ kb,   // [B][N][C]
    const __hip_bfloat16* __restrict__ vT,   // [B][C][N] key-permuted
    const __hip_bfloat16* __restrict__ mb,   // maskb coalesced layout
    unsigned* __restrict__ pOb,              // [B][196][CH][16 rows][4 pairs][32] u32
    float* __restrict__ pML)                 // [B][196][CH][2][16]
{
  __shared__ __hip_bfloat16 Kl[2][32 * 256];   // 2 x 16KB
  __shared__ __hip_bfloat16 Vl[2][32 * 256];   // 2 x 16KB

  const int bid   = blockIdx.x;       // 0..207
  const int grp   = bid % 16;
  const int qblk  = bid / 16;         // 0..12
  const int b     = grp / CH_;
  const int chunk = grp % CH_;
  const int wave  = threadIdx.x >> 6;
  const int lane  = threadIdx.x & 63;
  const int cl = lane & 31, hi = lane >> 5;
  const int qunit = qblk * 8 + wave;           // 32-row q unit
  const bool valid = qunit < 98;
  const int qu = valid ? qunit : 97;
  const int q0row = qu * 32 + cl;
  const int t0 = (chunk * NKV_) / CH_;
  const int t1 = ((chunk + 1) * NKV_) / CH_;
  const int nt = t1 - t0;
  const int tid = threadIdx.x;

  const __hip_bfloat16* qbb = qb + (size_t)b * N_ * C_;
  const char* kbbc = (const char*)(kb + (size_t)b * N_ * C_);
  const char* vbbc = (const char*)(vT + (size_t)b * C_ * N_);
  const char* mbase = (const char*)mb + (size_t)qu * (NKV_ * 2048) + cl * 64 + hi * 32;

  // Q fragments: B-operand, lane holds Q[q0row][ks*16 + 8*hi + j]
  bf16x8 qa[16];
#pragma unroll
  for (int ks = 0; ks < 16; ++ks)
    qa[ks] = *(const bf16x8*)(qbb + (size_t)q0row * C_ + ks * 16 + 8 * hi);

  f32x16 o[8];
#pragma unroll
  for (int ct = 0; ct < 8; ++ct)
#pragma unroll
    for (int r = 0; r < 16; ++r) o[ct][r] = 0.f;
  float lsum = 0.f;

  // stage K/V tile t into buffer buf: 4 gld16 per thread (512 threads)
  auto STAGE = [&](int buf, int t) {
    const char* ks0 = kbbc + (size_t)t * 32 * 512;
#pragma unroll
    for (int i = 0; i < 2; ++i) {
      int g2 = tid + i * 512;
      int ks = g2 >> 6, h2 = (g2 >> 5) & 1, key = g2 & 31;
      gld16(ks0 + key * 512 + ks * 32 + h2 * 16, (char*)&Kl[buf][0] + g2 * 16);
    }
    const char* vs0 = vbbc + (size_t)t * 64;   // k0*2 bytes
#pragma unroll
    for (int i = 0; i < 2; ++i) {
      int g2 = tid + i * 512;
      int st = g2 >> 9, h2 = (g2 >> 8) & 1, c = g2 & 255;
      gld16(vs0 + (size_t)c * (N_ * 2) + st * 32 + h2 * 16, (char*)&Vl[buf][0] + g2 * 16);
    }
  };

  union { uint4 v[2]; unsigned w[8]; } mm;
  auto MLOAD = [&](int t) {
    mm.v[0] = *(const uint4*)(mbase + (size_t)t * 2048);
    mm.v[1] = *(const uint4*)(mbase + (size_t)t * 2048 + 16);
  };

  STAGE(0, t0);
  MLOAD(t0);

  const int kread = hi * 512 + cl * 16;
  const int vread = hi * 4096 + cl * 16;

  for (int tt = 0; tt < nt; ++tt) {
    const int buf = tt & 1;
    const bool nl = (tt + 1 < nt);
    if (nl) STAGE(buf ^ 1, t0 + tt + 1);
    if (nl) asm volatile("s_waitcnt vmcnt(4)" ::: "memory");  // K/V/M(t) done; 4 new in flight
    else    asm volatile("s_waitcnt vmcnt(0)" ::: "memory");
    __builtin_amdgcn_s_barrier();

    f32x16 s;
#pragma unroll
    for (int r = 0; r < 16; ++r) s[r] = 0.f;
    if (valid) {
      const char* Kb = (const char*)&Kl[buf][0] + kread;
      __builtin_amdgcn_s_setprio(1);
#pragma unroll
      for (int ks = 0; ks < 16; ++ks) {
        bf16x8 kf = *(const bf16x8*)(Kb + ks * 1024);
        s = __builtin_amdgcn_mfma_f32_32x32x16_bf16(kf, qa[ks], s, 0, 0, 0);
      }
      __builtin_amdgcn_s_setprio(0);
    }

    if (valid) {
      // ---- fixed-max softmax, fully in-register ----
      float p[16];
#pragma unroll
      for (int j = 0; j < 16; ++j) {
        unsigned wo = mm.w[j >> 1];
        float mf = __uint_as_float((j & 1) ? (wo & 0xffff0000u) : (wo << 16));
        p[j] = exp2f(fmaf(s[j], SCALE2, mf) - FMAX_);
      }
      lsum += ((p[0]+p[1])+(p[2]+p[3])) + ((p[4]+p[5])+(p[6]+p[7]))
            + ((p[8]+p[9])+(p[10]+p[11])) + ((p[12]+p[13])+(p[14]+p[15]));

      // ---- P -> bf16 A-frags directly (V key-permuted; zero exchange) ----
      union { unsigned u[4]; bf16x8 v8; } A0, A1;
#pragma unroll
      for (int k = 0; k < 4; ++k) A0.u[k] = cvtpk(p[2 * k], p[2 * k + 1]);
#pragma unroll
      for (int k = 0; k < 4; ++k) A1.u[k] = cvtpk(p[8 + 2 * k], p[9 + 2 * k]);

      // ---- O += P @ V ----
      const char* Vb = (const char*)&Vl[buf][0] + vread;
      __builtin_amdgcn_s_setprio(1);
#pragma unroll
      for (int ct = 0; ct < 8; ++ct) {
        bf16x8 vf0 = *(const bf16x8*)(Vb + ct * 512);
        o[ct] = __builtin_amdgcn_mfma_f32_32x32x16_bf16(A0.v8, vf0, o[ct], 0, 0, 0);
        bf16x8 vf1 = *(const bf16x8*)(Vb + 8192 + ct * 512);
        o[ct] = __builtin_amdgcn_mfma_f32_32x32x16_bf16(A1.v8, vf1, o[ct], 0, 0, 0);
      }
      __builtin_amdgcn_s_setprio(0);
    }
    if (nl) MLOAD(t0 + tt + 1);
    __builtin_amdgcn_s_barrier();
  }

  if (valid) {
    float lt = lsum + __shfl_xor(lsum, 32);
#pragma unroll
    for (int r = 0; r < 16; ++r) {
      int q = (r & 3) + 8 * (r >> 2) + 4 * hi;
      int qt16 = qu * 2 + (q >> 4);
      int row = q & 15;
      size_t ob = ((((size_t)b * QT_ + qt16) * CH_ + chunk) * 2048) + row * 128 + cl;
#pragma unroll
      for (int pp = 0; pp < 4; ++pp)
        pOb[ob + pp * 32] = cvtpk(o[2 * pp][r], o[2 * pp + 1][r]);
    }
    if (lane < 32) {
      int qt16 = qu * 2 + (cl >> 4);
      int row = cl & 15;
      float* pml = pML + (((size_t)b * QT_ + qt16) * CH_ + chunk) * 32;
      pml[row] = FMAX_;
      pml[16 + row] = lt;
    }
  }
}

// ---- combine CH partials (coalesced): thread t <-> word w = t&127 of rows t>>7 ----
__global__ __launch_bounds__(256) void combine_kernel(
    const unsigned* __restrict__ pOb, const float* __restrict__ pML,
    const __hip_bfloat16* __restrict__ fb,
    __hip_bfloat16* __restrict__ ref)
{
  __shared__ float sml[CH_ * 32];
  const int b = blockIdx.y;
  const int qtile = blockIdx.x;
  const int tid = threadIdx.x;
  const float* pml = pML + ((size_t)b * QT_ + qtile) * (CH_ * 32);
  if (tid < CH_ * 32) sml[tid] = pml[tid];
  __syncthreads();

  const int w  = tid & 127;
  const int r0 = (tid >> 7) * 8;
  const int ch_lo = 64 * (w >> 5) + (w & 31);
  const int ch_hi = ch_lo + 32;

  float wgt[CH_][8];
#pragma unroll
  for (int r = 0; r < 8; ++r) {
    int row = r0 + r;
    float M = sml[row];
#pragma unroll
    for (int ch = 1; ch < CH_; ++ch) M = fmaxf(M, sml[ch * 32 + row]);
    float L = 0.f;
#pragma unroll
    for (int ch = 0; ch < CH_; ++ch) {
      float wv = exp2f(sml[ch * 32 + row] - M);
      wgt[ch][r] = wv;
      L += wv * sml[ch * 32 + 16 + row];
    }
    float iL = 1.f / L;
#pragma unroll
    for (int ch = 0; ch < CH_; ++ch) wgt[ch][r] *= iL;
  }

  float acc_lo[8], acc_hi[8];
#pragma unroll
  for (int r = 0; r < 8; ++r) { acc_lo[r] = 0.f; acc_hi[r] = 0.f; }
  const unsigned* base = pOb + ((size_t)b * QT_ + qtile) * (CH_ * 2048) + r0 * 128 + w;
#pragma unroll
  for (int ch = 0; ch < CH_; ++ch) {
    const unsigned* p = base + ch * 2048;
#pragma unroll
    for (int r = 0; r < 8; ++r) {
      unsigned u = p[r * 128];
      acc_lo[r] += wgt[ch][r] * __uint_as_float(u << 16);
      acc_hi[r] += wgt[ch][r] * __uint_as_float(u & 0xffff0000u);
    }
  }

  const __hip_bfloat16* f = fb + ((size_t)b * N_ + qtile * 16 + r0) * C_;
  __hip_bfloat16* rf = ref + ((size_t)b * N_ + qtile * 16 + r0) * C_;
#pragma unroll
  for (int r = 0; r < 8; ++r) {
    rf[r * C_ + ch_lo] = __float2bfloat16(acc_lo[r] + __bfloat162float(f[r * C_ + ch_lo]));
    rf[r * C_ + ch_hi] = __float2bfloat16(acc_hi[r] + __bfloat162float(f[r * C_ + ch_hi]));
  }
}

// ---- out[c][n] = Wl[:, :256] @ refined^T + Wl[:, 256:] @ f^T + bl ----
// grid (98, 2, 4): block = 128 c x 32 n; wave = 32 c; acc[2][2]
__global__ __launch_bounds__(256) void out_linear_kernel(
    const __hip_bfloat16* __restrict__ refb,
    const __hip_bfloat16* __restrict__ fb,
    const __hip_bfloat16* __restrict__ Wl,   // fragment-linear [ct][kk][lane][8]
    const float* __restrict__ bl,
    float* __restrict__ out)
{
  const int b    = blockIdx.z;
  const int cblk = blockIdx.y;
  const int nblk = blockIdx.x;
  const int wave = threadIdx.x >> 6;
  const int lane = threadIdx.x & 63;
  const int qt = lane & 15, g = lane >> 4;
  const int c0 = cblk * 128 + wave * 32;
  const int n0 = nblk * 32;
  const __hip_bfloat16* rb  = refb + (size_t)b * N_ * C_;
  const __hip_bfloat16* fbb = fb  + (size_t)b * N_ * C_;
  f32x4 acc[2][2];
#pragma unroll
  for (int u = 0; u < 2; ++u)
#pragma unroll
    for (int j = 0; j < 2; ++j) acc[u][j] = (f32x4){0.f, 0.f, 0.f, 0.f};
#pragma unroll
  for (int kk = 0; kk < 16; ++kk) {
    int ko2 = (kk * 32 + g * 8) & 255;
    const __hip_bfloat16* src = (kk < 8) ? rb : fbb;
    bf16x8 bb0 = *(const bf16x8*)(src + (size_t)(n0 + qt) * C_ + ko2);
    bf16x8 bb1 = *(const bf16x8*)(src + (size_t)(n0 + 16 + qt) * C_ + ko2);
#pragma unroll
    for (int u = 0; u < 2; ++u) {
      int ct = cblk * 8 + wave * 2 + u;
      bf16x8 a = *(const bf16x8*)(Wl + (size_t)((ct * 16 + kk) * 64 + lane) * 8);
      acc[u][0] = __builtin_amdgcn_mfma_f32_16x16x32_bf16(a, bb0, acc[u][0], 0, 0, 0);
      acc[u][1] = __builtin_amdgcn_mfma_f32_16x16x32_bf16(a, bb1, acc[u][1], 0, 0, 0);
    }
  }
  float* ob = out + (size_t)b * 4 * C_ * N_;
#pragma unroll
  for (int u = 0; u < 2; ++u)
#pragma unroll
    for (int j = 0; j < 2; ++j)
#pragma unroll
      for (int r = 0; r < 4; ++r) {
        int c = c0 + u * 16 + 4 * g + r;
        int n = n0 + j * 16 + qt;
        ob[(size_t)c * N_ + n] = acc[u][j][r] + bl[c];
      }
}

extern "C" void kernel_launch(void* const* d_in, const int* in_sizes, int n_in,
                              void* d_out, int out_size, void* d_ws, size_t ws_size,
                              hipStream_t stream) {
  (void)in_sizes; (void)n_in; (void)out_size; (void)ws_size;
  const float* feat0 = (const float*)d_in[0];
  const float* feat1 = (const float*)d_in[1];
  const float* feat2 = (const float*)d_in[2];
  const float* feat3 = (const float*)d_in[3];
  const float* mask  = (const float*)d_in[7];
  const float* Wv    = (const float*)d_in[8];
  const float* bv    = (const float*)d_in[9];
  const float* Wl    = (const float*)d_in[10];
  const float* bl    = (const float*)d_in[11];
  float* out = (float*)d_out;

  const size_t TOKB = (size_t)B_ * N_ * C_ * 2;  // 6,422,528
  char* w = (char*)d_ws;
  __hip_bfloat16* q0   = (__hip_bfloat16*)(w);
  __hip_bfloat16* f1   = (__hip_bfloat16*)(w + TOKB);
  __hip_bfloat16* f2   = (__hip_bfloat16*)(w + 2 * TOKB);
  __hip_bfloat16* f3   = (__hip_bfloat16*)(w + 3 * TOKB);
  __hip_bfloat16* vT0  = (__hip_bfloat16*)(w + 4 * TOKB);  // -> refined(0), refined(2)
  __hip_bfloat16* vT1  = (__hip_bfloat16*)(w + 5 * TOKB);  // -> refined(1)
  __hip_bfloat16* vT2  = (__hip_bfloat16*)(w + 6 * TOKB);
  char* w2 = w + 7 * TOKB;
  __hip_bfloat16* Wv_bf = (__hip_bfloat16*)(w2);
  __hip_bfloat16* Wl_bf = (__hip_bfloat16*)(w2 + 131072);
  __hip_bfloat16* maskb = (__hip_bfloat16*)(w2 + 393216);
  unsigned* pOb         = (unsigned*)(w2 + 393216 + 19668992);
  float* pML            = (float*)(w2 + 393216 + 19668992 + (size_t)B_ * QT_ * CH_ * 4096 * 2);

  dim3 tb(256);
  transpose4_kernel<<<dim3(98, 8, 16), tb, 0, stream>>>(feat0, feat1, feat2, feat3,
                                                        q0, f1, f2, f3, out);
  cvt_all_kernel<<<dim3((24576 + NKV_ * NKV_ * 64 + 255) / 256), tb, 0, stream>>>(
      Wv, Wl, mask, Wv_bf, Wl_bf, maskb);
  v_linear_kernel<<<dim3(49, 4, 3), tb, 0, stream>>>(f1, f2, f3, Wv_bf, bv,
                                                     vT0, vT1, vT2);

  const __hip_bfloat16* fs[3] = {f1, f2, f3};
  const __hip_bfloat16* vTs[3] = {vT0, vT1, vT2};
  __hip_bfloat16* refs[3] = {vT0, vT1, vT0};   // aliased: vT_s dead after attn(s)
  const __hip_bfloat16* q = q0;
  for (int s = 0; s < 3; ++s) {
    attn_kernel<<<dim3(13 * 4 * CH_), dim3(512), 0, stream>>>(q, fs[s], vTs[s], maskb, pOb, pML);
    combine_kernel<<<dim3(196, 4), tb, 0, stream>>>(pOb, pML, fs[s], refs[s]);
    out_linear_kernel<<<dim3(98, 2, 4), tb, 0, stream>>>(refs[s], fs[s], Wl_bf, bl,
                                                         out + (size_t)(s + 1) * C_ * N_);
    q = refs[s];
  }
}

// Round 15
// 340.783 us; speedup vs baseline: 1.0338x; 1.0338x over previous
//
#include <hip/hip_runtime.h>
#include <hip/hip_bf16.h>

// Problem constants
#define B_   4
#define C_   256
#define N_   3136
#define QT_  196     // N/16 q-tiles per batch
#define NKV_ 98      // N/32 kv tiles
#define CH_  5       // KV chunks (proven r10/r13 config)

typedef __attribute__((ext_vector_type(8)))  short bf16x8;
typedef __attribute__((ext_vector_type(4)))  float f32x4;
typedef __attribute__((ext_vector_type(16))) float f32x16;

#define LOG2E  1.4426950408889634f
#define SCALE2 (LOG2E / 16.0f)     // (1/sqrt(C)) * log2(e)
#define FMAX_  20.0f               // fixed softmax max (log2 domain); logits*log2e < ~12.3

__device__ __forceinline__ unsigned short bfbits(float f) {
  __hip_bfloat16 h = __float2bfloat16(f);
  return *(unsigned short*)&h;
}
__device__ __forceinline__ unsigned cvtpk(float lo, float hi) {
  unsigned r;
  asm("v_cvt_pk_bf16_f32 %0, %1, %2" : "=v"(r) : "v"(lo), "v"(hi));
  return r;
}

// ---- async global->LDS 16B helper (dest must be linear: base + lane*16) ----
__device__ __forceinline__ void gld16(const void* g, void* l) {
  __builtin_amdgcn_global_load_lds(
      (const __attribute__((address_space(1))) unsigned int*)g,
      (__attribute__((address_space(3))) unsigned int*)l, 16, 0, 0);
}

// key-column permutation inside each 32-group (PV zero-exchange layout)
__device__ __forceinline__ int vperm(int n) {
  int k = n & 31;
  return (n & ~31) | (k & 16) | (((k >> 2) & 1) << 3) | (k & 3) | (((k >> 3) & 1) << 2);
}

// ---- all 4 feats: [b][c][n] f32 -> [b][n][c] bf16; feat0 also copied to out slot 0 ----
__global__ __launch_bounds__(256) void transpose4_kernel(
    const float* __restrict__ f0, const float* __restrict__ f1,
    const float* __restrict__ f2, const float* __restrict__ f3,
    __hip_bfloat16* __restrict__ d0, __hip_bfloat16* __restrict__ d1,
    __hip_bfloat16* __restrict__ d2, __hip_bfloat16* __restrict__ d3,
    float* __restrict__ out) {
  __shared__ float tile[32][33];
  const int z  = blockIdx.z;
  const int fi = z >> 2;
  const int b  = z & 3;
  const float* src = (fi == 0) ? f0 : (fi == 1) ? f1 : (fi == 2) ? f2 : f3;
  __hip_bfloat16* dst = (fi == 0) ? d0 : (fi == 1) ? d1 : (fi == 2) ? d2 : d3;
  const int n0 = blockIdx.x * 32;
  const int c0 = blockIdx.y * 32;
  const int tx = threadIdx.x & 31;
  const int ty = threadIdx.x >> 5;
  const float* s = src + (size_t)b * C_ * N_;
  float* ob = out + (size_t)b * 4 * C_ * N_;
#pragma unroll
  for (int i = 0; i < 4; ++i) {
    int c = c0 + ty + i * 8;
    float v = s[(size_t)c * N_ + n0 + tx];
    tile[ty + i * 8][tx] = v;
    if (fi == 0) ob[(size_t)c * N_ + n0 + tx] = v;
  }
  __syncthreads();
  __hip_bfloat16* d = dst + (size_t)b * N_ * C_;
#pragma unroll
  for (int i = 0; i < 4; ++i) {
    int n = n0 + ty + i * 8;
    d[(size_t)n * C_ + c0 + tx] = __float2bfloat16(tile[tx][ty + i * 8]);
  }
}

// ---- converts ----
// Wv/Wl -> MFMA-fragment-linear bf16: W[ct][kk][lane(g*16+qt)][8 elems]
// mask -> coalesced per-wave-tile bf16 layout:
//   maskb[qu][kt][cl][hi][s] = mask[qu*32+cl][kt*32 + (s&3)+8*(s>>2)+4*hi] * LOG2E
__global__ __launch_bounds__(256) void cvt_all_kernel(
    const float* __restrict__ Wv, const float* __restrict__ Wl,
    const float* __restrict__ mask,
    __hip_bfloat16* __restrict__ Wvb, __hip_bfloat16* __restrict__ Wlb,
    __hip_bfloat16* __restrict__ maskb) {
  int i = blockIdx.x * 256 + threadIdx.x;
  if (i < 24576) {
    const float* src; __hip_bfloat16* dstp; int off, dst8;
    if (i < 8192) {
      off = i; src = Wv; dstp = Wvb;
      int row = off >> 5, c8 = off & 31;            // K=256: 32 groups/row
      int ct = row >> 4, qt = row & 15, kk = c8 >> 2, g = c8 & 3;
      dst8 = (ct * 8 + kk) * 64 + g * 16 + qt;
    } else {
      off = i - 8192; src = Wl; dstp = Wlb;
      int row = off >> 6, c8 = off & 63;            // K=512: 64 groups/row
      int ct = row >> 4, qt = row & 15, kk = c8 >> 2, g = c8 & 3;
      dst8 = (ct * 16 + kk) * 64 + g * 16 + qt;
    }
    const float4* s4 = (const float4*)src;
    float4 a = s4[2 * off], b = s4[2 * off + 1];
    union { unsigned short u[8]; bf16x8 v; } p;
    p.u[0]=bfbits(a.x); p.u[1]=bfbits(a.y); p.u[2]=bfbits(a.z); p.u[3]=bfbits(a.w);
    p.u[4]=bfbits(b.x); p.u[5]=bfbits(b.y); p.u[6]=bfbits(b.z); p.u[7]=bfbits(b.w);
    *(bf16x8*)(dstp + 8 * dst8) = p.v;
    return;
  }
  int j = i - 24576;
  if (j >= NKV_ * NKV_ * 32 * 2) return;   // 98*98*32*2
  const int hi  = j & 1;
  const int cl  = (j >> 1) & 31;
  const int rem = j >> 6;          // qu*98 + kt
  const int kt  = rem % NKV_;
  const int qu  = rem / NKV_;
  const int q   = qu * 32 + cl;
  const float* s = mask + (size_t)q * N_ + kt * 32 + 4 * hi;
  float4 a0 = *(const float4*)(s);
  float4 a1 = *(const float4*)(s + 8);
  float4 a2 = *(const float4*)(s + 16);
  float4 a3 = *(const float4*)(s + 24);
  union { unsigned short u[16]; bf16x8 v[2]; } p;
  p.u[0]=bfbits(a0.x*LOG2E); p.u[1]=bfbits(a0.y*LOG2E); p.u[2]=bfbits(a0.z*LOG2E); p.u[3]=bfbits(a0.w*LOG2E);
  p.u[4]=bfbits(a1.x*LOG2E); p.u[5]=bfbits(a1.y*LOG2E); p.u[6]=bfbits(a1.z*LOG2E); p.u[7]=bfbits(a1.w*LOG2E);
  p.u[8]=bfbits(a2.x*LOG2E); p.u[9]=bfbits(a2.y*LOG2E); p.u[10]=bfbits(a2.z*LOG2E); p.u[11]=bfbits(a2.w*LOG2E);
  p.u[12]=bfbits(a3.x*LOG2E); p.u[13]=bfbits(a3.y*LOG2E); p.u[14]=bfbits(a3.z*LOG2E); p.u[15]=bfbits(a3.w*LOG2E);
  __hip_bfloat16* d = maskb + ((size_t)rem * 32 + cl) * 32 + hi * 16;
  *(bf16x8*)(d)     = p.v[0];
  *(bf16x8*)(d + 8) = p.v[1];
}

// ---- vT_s[b][c][nperm] = Wv @ f_s^T + bv, all 3 stages in one launch ----
__global__ __launch_bounds__(256) void v_linear_kernel(
    const __hip_bfloat16* __restrict__ f1, const __hip_bfloat16* __restrict__ f2,
    const __hip_bfloat16* __restrict__ f3,
    const __hip_bfloat16* __restrict__ Wv,   // fragment-linear
    const float* __restrict__ bv,
    __hip_bfloat16* __restrict__ vT0, __hip_bfloat16* __restrict__ vT1,
    __hip_bfloat16* __restrict__ vT2)
{
  const int s    = blockIdx.z;
  const int b    = blockIdx.y;
  const int nblk = blockIdx.x;
  const __hip_bfloat16* fb = (s == 0) ? f1 : (s == 1) ? f2 : f3;
  __hip_bfloat16* vT = (s == 0) ? vT0 : (s == 1) ? vT1 : vT2;
  const int wave = threadIdx.x >> 6;
  const int lane = threadIdx.x & 63;
  const int qt = lane & 15, g = lane >> 4;
  const int n0 = nblk * 64;
  const __hip_bfloat16* fbb = fb + (size_t)b * N_ * C_;
  const int c0 = wave * 64;
  f32x4 acc[4][4];
#pragma unroll
  for (int u = 0; u < 4; ++u)
#pragma unroll
    for (int j = 0; j < 4; ++j) acc[u][j] = (f32x4){0.f, 0.f, 0.f, 0.f};
#pragma unroll
  for (int kk = 0; kk < 8; ++kk) {
    int ko = kk * 32 + g * 8;
    bf16x8 bb[4];
#pragma unroll
    for (int j = 0; j < 4; ++j)
      bb[j] = *(const bf16x8*)(fbb + (size_t)(n0 + j * 16 + qt) * C_ + ko);
#pragma unroll
    for (int u = 0; u < 4; ++u) {
      bf16x8 a = *(const bf16x8*)(Wv + (size_t)(((wave * 4 + u) * 8 + kk) * 64 + lane) * 8);
#pragma unroll
      for (int j = 0; j < 4; ++j)
        acc[u][j] = __builtin_amdgcn_mfma_f32_16x16x32_bf16(a, bb[j], acc[u][j], 0, 0, 0);
    }
  }
  __hip_bfloat16* outp = vT + (size_t)b * C_ * N_;
#pragma unroll
  for (int u = 0; u < 4; ++u)
#pragma unroll
    for (int j = 0; j < 4; ++j)
#pragma unroll
      for (int r = 0; r < 4; ++r) {
        int c = c0 + u * 16 + 4 * g + r;
        int n = vperm(n0 + j * 16 + qt);
        outp[(size_t)c * N_ + n] = __float2bfloat16(acc[u][j][r] + bv[c]);
      }
}

// ---- flash attention (r13 schedule; XCD-aware mask co-location remap) ----
// mask-group m = qblk*5+chunk; all 4 b-instances of m share bid%8 -> same XCD.
__global__ __launch_bounds__(256, 2) void attn_kernel(
    const __hip_bfloat16* __restrict__ qb,   // [B][N][C]
    const __hip_bfloat16* __restrict__ kb,   // [B][N][C]
    const __hip_bfloat16* __restrict__ vT,   // [B][C][N] key-permuted
    const __hip_bfloat16* __restrict__ mb,   // maskb coalesced layout
    unsigned* __restrict__ pOb,              // [B][196][CH][16 rows][4 pairs][32] u32
    float* __restrict__ pML)                 // [B][196][CH][2][16]
{
  __shared__ __hip_bfloat16 Kl[2][32 * 256];   // 2 x 16KB
  __shared__ __hip_bfloat16 Vl[2][32 * 256];   // 2 x 16KB

  const int x = blockIdx.x & 7, y = blockIdx.x >> 3;   // grid 512
  const int m = ((y >> 2) << 3) + x;                   // mask-group 0..127
  if (m >= 125) return;                                // 12 holes, exit pre-barrier
  const int b     = y & 3;
  const int qblk  = m / CH_;          // 0..24
  const int chunk = m % CH_;
  const int wave  = threadIdx.x >> 6;
  const int lane  = threadIdx.x & 63;
  const int cl = lane & 31, hi = lane >> 5;
  const int qunit = qblk * 4 + wave;           // 32-row q unit
  const bool valid = qunit < 98;
  const int qu = valid ? qunit : 97;
  const int q0row = qu * 32 + cl;
  const int t0 = (chunk * NKV_) / CH_;
  const int t1 = ((chunk + 1) * NKV_) / CH_;
  const int nt = t1 - t0;
  const int tid = threadIdx.x;

  const __hip_bfloat16* qbb = qb + (size_t)b * N_ * C_;
  const char* kbbc = (const char*)(kb + (size_t)b * N_ * C_);
  const char* vbbc = (const char*)(vT + (size_t)b * C_ * N_);
  const char* mbase = (const char*)mb + (size_t)qu * (NKV_ * 2048) + cl * 64 + hi * 32;

  // Q fragments: B-operand, lane holds Q[q0row][ks*16 + 8*hi + j]
  bf16x8 qa[16];
#pragma unroll
  for (int ks = 0; ks < 16; ++ks)
    qa[ks] = *(const bf16x8*)(qbb + (size_t)q0row * C_ + ks * 16 + 8 * hi);

  f32x16 o[8];
#pragma unroll
  for (int ct = 0; ct < 8; ++ct)
#pragma unroll
    for (int r = 0; r < 16; ++r) o[ct][r] = 0.f;
  float lsum = 0.f;

  // stage K/V tile t into buffer buf: 8 gld16 per thread
  auto STAGE = [&](int buf, int t) {
    const char* ks0 = kbbc + (size_t)t * 32 * 512;
#pragma unroll
    for (int i = 0; i < 4; ++i) {
      int g2 = tid + i * 256;
      int ks = g2 >> 6, h2 = (g2 >> 5) & 1, key = g2 & 31;
      gld16(ks0 + key * 512 + ks * 32 + h2 * 16, (char*)&Kl[buf][0] + g2 * 16);
    }
    const char* vs0 = vbbc + (size_t)t * 64;   // k0*2 bytes
#pragma unroll
    for (int i = 0; i < 4; ++i) {
      int g2 = tid + i * 256;
      int st = g2 >> 9, h2 = (g2 >> 8) & 1, c = g2 & 255;
      gld16(vs0 + (size_t)c * (N_ * 2) + st * 32 + h2 * 16, (char*)&Vl[buf][0] + g2 * 16);
    }
  };

  union { uint4 v[2]; unsigned w[8]; } mm;
  auto MLOAD = [&](int t) {
    mm.v[0] = *(const uint4*)(mbase + (size_t)t * 2048);
    mm.v[1] = *(const uint4*)(mbase + (size_t)t * 2048 + 16);
  };

  STAGE(0, t0);
  MLOAD(t0);

  const int kread = hi * 512 + cl * 16;
  const int vread = hi * 4096 + cl * 16;

  for (int tt = 0; tt < nt; ++tt) {
    const int buf = tt & 1;
    const bool nl = (tt + 1 < nt);
    if (nl) STAGE(buf ^ 1, t0 + tt + 1);
    if (nl) asm volatile("s_waitcnt vmcnt(10)" ::: "memory");
    else    asm volatile("s_waitcnt vmcnt(2)"  ::: "memory");
    __builtin_amdgcn_s_barrier();

    f32x16 s;
#pragma unroll
    for (int r = 0; r < 16; ++r) s[r] = 0.f;
    if (valid) {
      const char* Kb = (const char*)&Kl[buf][0] + kread;
      __builtin_amdgcn_s_setprio(1);
#pragma unroll
      for (int ks = 0; ks < 16; ++ks) {
        bf16x8 kf = *(const bf16x8*)(Kb + ks * 1024);
        s = __builtin_amdgcn_mfma_f32_32x32x16_bf16(kf, qa[ks], s, 0, 0, 0);
      }
      __builtin_amdgcn_s_setprio(0);
    }

    if (valid) {
      // ---- fixed-max softmax, fully in-register ----
      float p[16];
#pragma unroll
      for (int j = 0; j < 16; ++j) {
        unsigned wo = mm.w[j >> 1];
        float mf = __uint_as_float((j & 1) ? (wo & 0xffff0000u) : (wo << 16));
        p[j] = exp2f(fmaf(s[j], SCALE2, mf) - FMAX_);
      }
      lsum += ((p[0]+p[1])+(p[2]+p[3])) + ((p[4]+p[5])+(p[6]+p[7]))
            + ((p[8]+p[9])+(p[10]+p[11])) + ((p[12]+p[13])+(p[14]+p[15]));

      // ---- P -> bf16 A-frags directly (V key-permuted; zero exchange) ----
      union { unsigned u[4]; bf16x8 v8; } A0, A1;
#pragma unroll
      for (int k = 0; k < 4; ++k) A0.u[k] = cvtpk(p[2 * k], p[2 * k + 1]);
#pragma unroll
      for (int k = 0; k < 4; ++k) A1.u[k] = cvtpk(p[8 + 2 * k], p[9 + 2 * k]);

      // ---- O += P @ V ----
      const char* Vb = (const char*)&Vl[buf][0] + vread;
      __builtin_amdgcn_s_setprio(1);
#pragma unroll
      for (int ct = 0; ct < 8; ++ct) {
        bf16x8 vf0 = *(const bf16x8*)(Vb + ct * 512);
        o[ct] = __builtin_amdgcn_mfma_f32_32x32x16_bf16(A0.v8, vf0, o[ct], 0, 0, 0);
        bf16x8 vf1 = *(const bf16x8*)(Vb + 8192 + ct * 512);
        o[ct] = __builtin_amdgcn_mfma_f32_32x32x16_bf16(A1.v8, vf1, o[ct], 0, 0, 0);
      }
      __builtin_amdgcn_s_setprio(0);
    }
    if (nl) MLOAD(t0 + tt + 1);
    __builtin_amdgcn_s_barrier();
  }

  if (valid) {
    float lt = lsum + __shfl_xor(lsum, 32);
#pragma unroll
    for (int r = 0; r < 16; ++r) {
      int q = (r & 3) + 8 * (r >> 2) + 4 * hi;
      int qt16 = qu * 2 + (q >> 4);
      int row = q & 15;
      size_t ob = ((((size_t)b * QT_ + qt16) * CH_ + chunk) * 2048) + row * 128 + cl;
#pragma unroll
      for (int pp = 0; pp < 4; ++pp)
        pOb[ob + pp * 32] = cvtpk(o[2 * pp][r], o[2 * pp + 1][r]);
    }
    if (lane < 32) {
      int qt16 = qu * 2 + (cl >> 4);
      int row = cl & 15;
      float* pml = pML + (((size_t)b * QT_ + qt16) * CH_ + chunk) * 32;
      pml[row] = FMAX_;
      pml[16 + row] = lt;
    }
  }
}

// ---- combine CH partials (coalesced): thread t <-> word w = t&127 of rows t>>7 ----
__global__ __launch_bounds__(256) void combine_kernel(
    const unsigned* __restrict__ pOb, const float* __restrict__ pML,
    const __hip_bfloat16* __restrict__ fb,
    __hip_bfloat16* __restrict__ ref)
{
  __shared__ float sml[CH_ * 32];
  const int b = blockIdx.y;
  const int qtile = blockIdx.x;
  const int tid = threadIdx.x;
  const float* pml = pML + ((size_t)b * QT_ + qtile) * (CH_ * 32);
  if (tid < CH_ * 32) sml[tid] = pml[tid];
  __syncthreads();

  const int w  = tid & 127;
  const int r0 = (tid >> 7) * 8;
  const int ch_lo = 64 * (w >> 5) + (w & 31);
  const int ch_hi = ch_lo + 32;

  float wgt[CH_][8];
#pragma unroll
  for (int r = 0; r < 8; ++r) {
    int row = r0 + r;
    float M = sml[row];
#pragma unroll
    for (int ch = 1; ch < CH_; ++ch) M = fmaxf(M, sml[ch * 32 + row]);
    float L = 0.f;
#pragma unroll
    for (int ch = 0; ch < CH_; ++ch) {
      float wv = exp2f(sml[ch * 32 + row] - M);
      wgt[ch][r] = wv;
      L += wv * sml[ch * 32 + 16 + row];
    }
    float iL = 1.f / L;
#pragma unroll
    for (int ch = 0; ch < CH_; ++ch) wgt[ch][r] *= iL;
  }

  float acc_lo[8], acc_hi[8];
#pragma unroll
  for (int r = 0; r < 8; ++r) { acc_lo[r] = 0.f; acc_hi[r] = 0.f; }
  const unsigned* base = pOb + ((size_t)b * QT_ + qtile) * (CH_ * 2048) + r0 * 128 + w;
#pragma unroll
  for (int ch = 0; ch < CH_; ++ch) {
    const unsigned* p = base + ch * 2048;
#pragma unroll
    for (int r = 0; r < 8; ++r) {
      unsigned u = p[r * 128];
      acc_lo[r] += wgt[ch][r] * __uint_as_float(u << 16);
      acc_hi[r] += wgt[ch][r] * __uint_as_float(u & 0xffff0000u);
    }
  }

  const __hip_bfloat16* f = fb + ((size_t)b * N_ + qtile * 16 + r0) * C_;
  __hip_bfloat16* rf = ref + ((size_t)b * N_ + qtile * 16 + r0) * C_;
#pragma unroll
  for (int r = 0; r < 8; ++r) {
    rf[r * C_ + ch_lo] = __float2bfloat16(acc_lo[r] + __bfloat162float(f[r * C_ + ch_lo]));
    rf[r * C_ + ch_hi] = __float2bfloat16(acc_hi[r] + __bfloat162float(f[r * C_ + ch_hi]));
  }
}

// ---- out[c][n] = Wl[:, :256] @ refined^T + Wl[:, 256:] @ f^T + bl ----
// grid (98, 2, 4): block = 128 c x 32 n; wave = 32 c; acc[2][2]
__global__ __launch_bounds__(256) void out_linear_kernel(
    const __hip_bfloat16* __restrict__ refb,
    const __hip_bfloat16* __restrict__ fb,
    const __hip_bfloat16* __restrict__ Wl,   // fragment-linear [ct][kk][lane][8]
    const float* __restrict__ bl,
    float* __restrict__ out)
{
  const int b    = blockIdx.z;
  const int cblk = blockIdx.y;
  const int nblk = blockIdx.x;
  const int wave = threadIdx.x >> 6;
  const int lane = threadIdx.x & 63;
  const int qt = lane & 15, g = lane >> 4;
  const int c0 = cblk * 128 + wave * 32;
  const int n0 = nblk * 32;
  const __hip_bfloat16* rb  = refb + (size_t)b * N_ * C_;
  const __hip_bfloat16* fbb = fb  + (size_t)b * N_ * C_;
  f32x4 acc[2][2];
#pragma unroll
  for (int u = 0; u < 2; ++u)
#pragma unroll
    for (int j = 0; j < 2; ++j) acc[u][j] = (f32x4){0.f, 0.f, 0.f, 0.f};
#pragma unroll
  for (int kk = 0; kk < 16; ++kk) {
    int ko2 = (kk * 32 + g * 8) & 255;
    const __hip_bfloat16* src = (kk < 8) ? rb : fbb;
    bf16x8 bb0 = *(const bf16x8*)(src + (size_t)(n0 + qt) * C_ + ko2);
    bf16x8 bb1 = *(const bf16x8*)(src + (size_t)(n0 + 16 + qt) * C_ + ko2);
#pragma unroll
    for (int u = 0; u < 2; ++u) {
      int ct = cblk * 8 + wave * 2 + u;
      bf16x8 a = *(const bf16x8*)(Wl + (size_t)((ct * 16 + kk) * 64 + lane) * 8);
      acc[u][0] = __builtin_amdgcn_mfma_f32_16x16x32_bf16(a, bb0, acc[u][0], 0, 0, 0);
      acc[u][1] = __builtin_amdgcn_mfma_f32_16x16x32_bf16(a, bb1, acc[u][1], 0, 0, 0);
    }
  }
  float* ob = out + (size_t)b * 4 * C_ * N_;
#pragma unroll
  for (int u = 0; u < 2; ++u)
#pragma unroll
    for (int j = 0; j < 2; ++j)
#pragma unroll
      for (int r = 0; r < 4; ++r) {
        int c = c0 + u * 16 + 4 * g + r;
        int n = n0 + j * 16 + qt;
        ob[(size_t)c * N_ + n] = acc[u][j][r] + bl[c];
      }
}

extern "C" void kernel_launch(void* const* d_in, const int* in_sizes, int n_in,
                              void* d_out, int out_size, void* d_ws, size_t ws_size,
                              hipStream_t stream) {
  (void)in_sizes; (void)n_in; (void)out_size; (void)ws_size;
  const float* feat0 = (const float*)d_in[0];
  const float* feat1 = (const float*)d_in[1];
  const float* feat2 = (const float*)d_in[2];
  const float* feat3 = (const float*)d_in[3];
  const float* mask  = (const float*)d_in[7];
  const float* Wv    = (const float*)d_in[8];
  const float* bv    = (const float*)d_in[9];
  const float* Wl    = (const float*)d_in[10];
  const float* bl    = (const float*)d_in[11];
  float* out = (float*)d_out;

  const size_t TOKB = (size_t)B_ * N_ * C_ * 2;  // 6,422,528
  char* w = (char*)d_ws;
  __hip_bfloat16* q0   = (__hip_bfloat16*)(w);
  __hip_bfloat16* f1   = (__hip_bfloat16*)(w + TOKB);
  __hip_bfloat16* f2   = (__hip_bfloat16*)(w + 2 * TOKB);
  __hip_bfloat16* f3   = (__hip_bfloat16*)(w + 3 * TOKB);
  __hip_bfloat16* vT0  = (__hip_bfloat16*)(w + 4 * TOKB);  // -> refined(0), refined(2)
  __hip_bfloat16* vT1  = (__hip_bfloat16*)(w + 5 * TOKB);  // -> refined(1)
  __hip_bfloat16* vT2  = (__hip_bfloat16*)(w + 6 * TOKB);
  char* w2 = w + 7 * TOKB;
  __hip_bfloat16* Wv_bf = (__hip_bfloat16*)(w2);
  __hip_bfloat16* Wl_bf = (__hip_bfloat16*)(w2 + 131072);
  __hip_bfloat16* maskb = (__hip_bfloat16*)(w2 + 393216);
  unsigned* pOb         = (unsigned*)(w2 + 393216 + 19668992);
  float* pML            = (float*)(w2 + 393216 + 19668992 + (size_t)B_ * QT_ * CH_ * 4096 * 2);

  dim3 tb(256);
  transpose4_kernel<<<dim3(98, 8, 16), tb, 0, stream>>>(feat0, feat1, feat2, feat3,
                                                        q0, f1, f2, f3, out);
  cvt_all_kernel<<<dim3((24576 + NKV_ * NKV_ * 64 + 255) / 256), tb, 0, stream>>>(
      Wv, Wl, mask, Wv_bf, Wl_bf, maskb);
  v_linear_kernel<<<dim3(49, 4, 3), tb, 0, stream>>>(f1, f2, f3, Wv_bf, bv,
                                                     vT0, vT1, vT2);

  const __hip_bfloat16* fs[3] = {f1, f2, f3};
  const __hip_bfloat16* vTs[3] = {vT0, vT1, vT2};
  __hip_bfloat16* refs[3] = {vT0, vT1, vT0};   // aliased: vT_s dead after attn(s)
  const __hip_bfloat16* q = q0;
  for (int s = 0; s < 3; ++s) {
    attn_kernel<<<dim3(512), tb, 0, stream>>>(q, fs[s], vTs[s], maskb, pOb, pML);
    combine_kernel<<<dim3(196, 4), tb, 0, stream>>>(pOb, pML, fs[s], refs[s]);
    out_linear_kernel<<<dim3(98, 2, 4), tb, 0, stream>>>(refs[s], fs[s], Wl_bf, bl,
                                                         out + (size_t)(s + 1) * C_ * N_);
    q = refs[s];
  }
}

// Round 16
// 318.365 us; speedup vs baseline: 1.1066x; 1.0704x over previous
//
#include <hip/hip_runtime.h>
#include <hip/hip_bf16.h>

// Problem constants
#define B_   4
#define C_   256
#define N_   3136
#define QT_  196     // N/16 q-tiles per batch
#define NKV_ 98      // N/32 kv tiles
#define CH_  5       // KV chunks (proven r10/r13 config)

typedef __attribute__((ext_vector_type(8)))  short bf16x8;
typedef __attribute__((ext_vector_type(4)))  float f32x4;
typedef __attribute__((ext_vector_type(16))) float f32x16;

#define LOG2E  1.4426950408889634f
#define SCALE2 (LOG2E / 16.0f)     // (1/sqrt(C)) * log2(e)
#define FMAX_  20.0f               // fixed softmax max (log2 domain); logits*log2e < ~12.3

__device__ __forceinline__ unsigned short bfbits(float f) {
  __hip_bfloat16 h = __float2bfloat16(f);
  return *(unsigned short*)&h;
}
__device__ __forceinline__ unsigned cvtpk(float lo, float hi) {
  unsigned r;
  asm("v_cvt_pk_bf16_f32 %0, %1, %2" : "=v"(r) : "v"(lo), "v"(hi));
  return r;
}

// ---- async global->LDS 16B helper (dest must be linear: base + lane*16) ----
__device__ __forceinline__ void gld16(const void* g, void* l) {
  __builtin_amdgcn_global_load_lds(
      (const __attribute__((address_space(1))) unsigned int*)g,
      (__attribute__((address_space(3))) unsigned int*)l, 16, 0, 0);
}

// key-column permutation inside each 32-group (PV zero-exchange layout)
__device__ __forceinline__ int vperm(int n) {
  int k = n & 31;
  return (n & ~31) | (k & 16) | (((k >> 2) & 1) << 3) | (k & 3) | (((k >> 3) & 1) << 2);
}

// ---- all 4 feats: [b][c][n] f32 -> [b][n][c] bf16; feat0 also copied to out slot 0 ----
__global__ __launch_bounds__(256) void transpose4_kernel(
    const float* __restrict__ f0, const float* __restrict__ f1,
    const float* __restrict__ f2, const float* __restrict__ f3,
    __hip_bfloat16* __restrict__ d0, __hip_bfloat16* __restrict__ d1,
    __hip_bfloat16* __restrict__ d2, __hip_bfloat16* __restrict__ d3,
    float* __restrict__ out) {
  __shared__ float tile[32][33];
  const int z  = blockIdx.z;
  const int fi = z >> 2;
  const int b  = z & 3;
  const float* src = (fi == 0) ? f0 : (fi == 1) ? f1 : (fi == 2) ? f2 : f3;
  __hip_bfloat16* dst = (fi == 0) ? d0 : (fi == 1) ? d1 : (fi == 2) ? d2 : d3;
  const int n0 = blockIdx.x * 32;
  const int c0 = blockIdx.y * 32;
  const int tx = threadIdx.x & 31;
  const int ty = threadIdx.x >> 5;
  const float* s = src + (size_t)b * C_ * N_;
  float* ob = out + (size_t)b * 4 * C_ * N_;
#pragma unroll
  for (int i = 0; i < 4; ++i) {
    int c = c0 + ty + i * 8;
    float v = s[(size_t)c * N_ + n0 + tx];
    tile[ty + i * 8][tx] = v;
    if (fi == 0) ob[(size_t)c * N_ + n0 + tx] = v;
  }
  __syncthreads();
  __hip_bfloat16* d = dst + (size_t)b * N_ * C_;
#pragma unroll
  for (int i = 0; i < 4; ++i) {
    int n = n0 + ty + i * 8;
    d[(size_t)n * C_ + c0 + tx] = __float2bfloat16(tile[tx][ty + i * 8]);
  }
}

// ---- converts ----
// Wv/Wl -> MFMA-fragment-linear bf16: W[ct][kk][lane(g*16+qt)][8 elems]
// mask -> coalesced per-wave-tile bf16 layout:
//   maskb[qu][kt][cl][hi][s] = mask[qu*32+cl][kt*32 + (s&3)+8*(s>>2)+4*hi] * LOG2E
__global__ __launch_bounds__(256) void cvt_all_kernel(
    const float* __restrict__ Wv, const float* __restrict__ Wl,
    const float* __restrict__ mask,
    __hip_bfloat16* __restrict__ Wvb, __hip_bfloat16* __restrict__ Wlb,
    __hip_bfloat16* __restrict__ maskb) {
  int i = blockIdx.x * 256 + threadIdx.x;
  if (i < 24576) {
    const float* src; __hip_bfloat16* dstp; int off, dst8;
    if (i < 8192) {
      off = i; src = Wv; dstp = Wvb;
      int row = off >> 5, c8 = off & 31;            // K=256: 32 groups/row
      int ct = row >> 4, qt = row & 15, kk = c8 >> 2, g = c8 & 3;
      dst8 = (ct * 8 + kk) * 64 + g * 16 + qt;
    } else {
      off = i - 8192; src = Wl; dstp = Wlb;
      int row = off >> 6, c8 = off & 63;            // K=512: 64 groups/row
      int ct = row >> 4, qt = row & 15, kk = c8 >> 2, g = c8 & 3;
      dst8 = (ct * 16 + kk) * 64 + g * 16 + qt;
    }
    const float4* s4 = (const float4*)src;
    float4 a = s4[2 * off], b = s4[2 * off + 1];
    union { unsigned short u[8]; bf16x8 v; } p;
    p.u[0]=bfbits(a.x); p.u[1]=bfbits(a.y); p.u[2]=bfbits(a.z); p.u[3]=bfbits(a.w);
    p.u[4]=bfbits(b.x); p.u[5]=bfbits(b.y); p.u[6]=bfbits(b.z); p.u[7]=bfbits(b.w);
    *(bf16x8*)(dstp + 8 * dst8) = p.v;
    return;
  }
  int j = i - 24576;
  if (j >= NKV_ * NKV_ * 32 * 2) return;   // 98*98*32*2
  const int hi  = j & 1;
  const int cl  = (j >> 1) & 31;
  const int rem = j >> 6;          // qu*98 + kt
  const int kt  = rem % NKV_;
  const int qu  = rem / NKV_;
  const int q   = qu * 32 + cl;
  const float* s = mask + (size_t)q * N_ + kt * 32 + 4 * hi;
  float4 a0 = *(const float4*)(s);
  float4 a1 = *(const float4*)(s + 8);
  float4 a2 = *(const float4*)(s + 16);
  float4 a3 = *(const float4*)(s + 24);
  union { unsigned short u[16]; bf16x8 v[2]; } p;
  p.u[0]=bfbits(a0.x*LOG2E); p.u[1]=bfbits(a0.y*LOG2E); p.u[2]=bfbits(a0.z*LOG2E); p.u[3]=bfbits(a0.w*LOG2E);
  p.u[4]=bfbits(a1.x*LOG2E); p.u[5]=bfbits(a1.y*LOG2E); p.u[6]=bfbits(a1.z*LOG2E); p.u[7]=bfbits(a1.w*LOG2E);
  p.u[8]=bfbits(a2.x*LOG2E); p.u[9]=bfbits(a2.y*LOG2E); p.u[10]=bfbits(a2.z*LOG2E); p.u[11]=bfbits(a2.w*LOG2E);
  p.u[12]=bfbits(a3.x*LOG2E); p.u[13]=bfbits(a3.y*LOG2E); p.u[14]=bfbits(a3.z*LOG2E); p.u[15]=bfbits(a3.w*LOG2E);
  __hip_bfloat16* d = maskb + ((size_t)rem * 32 + cl) * 32 + hi * 16;
  *(bf16x8*)(d)     = p.v[0];
  *(bf16x8*)(d + 8) = p.v[1];
}

// ---- vT_s[b][c][nperm] = Wv @ f_s^T + bv, all 3 stages in one launch ----
__global__ __launch_bounds__(256) void v_linear_kernel(
    const __hip_bfloat16* __restrict__ f1, const __hip_bfloat16* __restrict__ f2,
    const __hip_bfloat16* __restrict__ f3,
    const __hip_bfloat16* __restrict__ Wv,   // fragment-linear
    const float* __restrict__ bv,
    __hip_bfloat16* __restrict__ vT0, __hip_bfloat16* __restrict__ vT1,
    __hip_bfloat16* __restrict__ vT2)
{
  const int s    = blockIdx.z;
  const int b    = blockIdx.y;
  const int nblk = blockIdx.x;
  const __hip_bfloat16* fb = (s == 0) ? f1 : (s == 1) ? f2 : f3;
  __hip_bfloat16* vT = (s == 0) ? vT0 : (s == 1) ? vT1 : vT2;
  const int wave = threadIdx.x >> 6;
  const int lane = threadIdx.x & 63;
  const int qt = lane & 15, g = lane >> 4;
  const int n0 = nblk * 64;
  const __hip_bfloat16* fbb = fb + (size_t)b * N_ * C_;
  const int c0 = wave * 64;
  f32x4 acc[4][4];
#pragma unroll
  for (int u = 0; u < 4; ++u)
#pragma unroll
    for (int j = 0; j < 4; ++j) acc[u][j] = (f32x4){0.f, 0.f, 0.f, 0.f};
#pragma unroll
  for (int kk = 0; kk < 8; ++kk) {
    int ko = kk * 32 + g * 8;
    bf16x8 bb[4];
#pragma unroll
    for (int j = 0; j < 4; ++j)
      bb[j] = *(const bf16x8*)(fbb + (size_t)(n0 + j * 16 + qt) * C_ + ko);
#pragma unroll
    for (int u = 0; u < 4; ++u) {
      bf16x8 a = *(const bf16x8*)(Wv + (size_t)(((wave * 4 + u) * 8 + kk) * 64 + lane) * 8);
#pragma unroll
      for (int j = 0; j < 4; ++j)
        acc[u][j] = __builtin_amdgcn_mfma_f32_16x16x32_bf16(a, bb[j], acc[u][j], 0, 0, 0);
    }
  }
  __hip_bfloat16* outp = vT + (size_t)b * C_ * N_;
#pragma unroll
  for (int u = 0; u < 4; ++u)
#pragma unroll
    for (int j = 0; j < 4; ++j)
#pragma unroll
      for (int r = 0; r < 4; ++r) {
        int c = c0 + u * 16 + 4 * g + r;
        int n = vperm(n0 + j * 16 + qt);
        outp[(size_t)c * N_ + n] = __float2bfloat16(acc[u][j][r] + bv[c]);
      }
}

// ======== attn block body (r13, exact) ========
__device__ __forceinline__ void attn_body(
    int bid,
    const __hip_bfloat16* __restrict__ qb, const __hip_bfloat16* __restrict__ kb,
    const __hip_bfloat16* __restrict__ vT, const __hip_bfloat16* __restrict__ mb,
    unsigned* __restrict__ pOb, float* __restrict__ pML)
{
  __shared__ __hip_bfloat16 Kl[2][32 * 256];   // 2 x 16KB
  __shared__ __hip_bfloat16 Vl[2][32 * 256];   // 2 x 16KB

  const int grp   = bid % 20;
  const int qblk  = bid / 20;         // 0..24
  const int b     = grp / CH_;
  const int chunk = grp % CH_;
  const int wave  = threadIdx.x >> 6;
  const int lane  = threadIdx.x & 63;
  const int cl = lane & 31, hi = lane >> 5;
  const int qunit = qblk * 4 + wave;           // 32-row q unit
  const bool valid = qunit < 98;
  const int qu = valid ? qunit : 97;
  const int q0row = qu * 32 + cl;
  const int t0 = (chunk * NKV_) / CH_;
  const int t1 = ((chunk + 1) * NKV_) / CH_;
  const int nt = t1 - t0;
  const int tid = threadIdx.x;

  const __hip_bfloat16* qbb = qb + (size_t)b * N_ * C_;
  const char* kbbc = (const char*)(kb + (size_t)b * N_ * C_);
  const char* vbbc = (const char*)(vT + (size_t)b * C_ * N_);
  const char* mbase = (const char*)mb + (size_t)qu * (NKV_ * 2048) + cl * 64 + hi * 32;

  bf16x8 qa[16];
#pragma unroll
  for (int ks = 0; ks < 16; ++ks)
    qa[ks] = *(const bf16x8*)(qbb + (size_t)q0row * C_ + ks * 16 + 8 * hi);

  f32x16 o[8];
#pragma unroll
  for (int ct = 0; ct < 8; ++ct)
#pragma unroll
    for (int r = 0; r < 16; ++r) o[ct][r] = 0.f;
  float lsum = 0.f;

  auto STAGE = [&](int buf, int t) {
    const char* ks0 = kbbc + (size_t)t * 32 * 512;
#pragma unroll
    for (int i = 0; i < 4; ++i) {
      int g2 = tid + i * 256;
      int ks = g2 >> 6, h2 = (g2 >> 5) & 1, key = g2 & 31;
      gld16(ks0 + key * 512 + ks * 32 + h2 * 16, (char*)&Kl[buf][0] + g2 * 16);
    }
    const char* vs0 = vbbc + (size_t)t * 64;
#pragma unroll
    for (int i = 0; i < 4; ++i) {
      int g2 = tid + i * 256;
      int st = g2 >> 9, h2 = (g2 >> 8) & 1, c = g2 & 255;
      gld16(vs0 + (size_t)c * (N_ * 2) + st * 32 + h2 * 16, (char*)&Vl[buf][0] + g2 * 16);
    }
  };

  union { uint4 v[2]; unsigned w[8]; } mm;
  auto MLOAD = [&](int t) {
    mm.v[0] = *(const uint4*)(mbase + (size_t)t * 2048);
    mm.v[1] = *(const uint4*)(mbase + (size_t)t * 2048 + 16);
  };

  STAGE(0, t0);
  MLOAD(t0);

  const int kread = hi * 512 + cl * 16;
  const int vread = hi * 4096 + cl * 16;

  for (int tt = 0; tt < nt; ++tt) {
    const int buf = tt & 1;
    const bool nl = (tt + 1 < nt);
    if (nl) STAGE(buf ^ 1, t0 + tt + 1);
    if (nl) asm volatile("s_waitcnt vmcnt(10)" ::: "memory");
    else    asm volatile("s_waitcnt vmcnt(2)"  ::: "memory");
    __builtin_amdgcn_s_barrier();

    f32x16 s;
#pragma unroll
    for (int r = 0; r < 16; ++r) s[r] = 0.f;
    if (valid) {
      const char* Kb = (const char*)&Kl[buf][0] + kread;
      __builtin_amdgcn_s_setprio(1);
#pragma unroll
      for (int ks = 0; ks < 16; ++ks) {
        bf16x8 kf = *(const bf16x8*)(Kb + ks * 1024);
        s = __builtin_amdgcn_mfma_f32_32x32x16_bf16(kf, qa[ks], s, 0, 0, 0);
      }
      __builtin_amdgcn_s_setprio(0);
    }

    if (valid) {
      float p[16];
#pragma unroll
      for (int j = 0; j < 16; ++j) {
        unsigned wo = mm.w[j >> 1];
        float mf = __uint_as_float((j & 1) ? (wo & 0xffff0000u) : (wo << 16));
        p[j] = exp2f(fmaf(s[j], SCALE2, mf) - FMAX_);
      }
      lsum += ((p[0]+p[1])+(p[2]+p[3])) + ((p[4]+p[5])+(p[6]+p[7]))
            + ((p[8]+p[9])+(p[10]+p[11])) + ((p[12]+p[13])+(p[14]+p[15]));

      union { unsigned u[4]; bf16x8 v8; } A0, A1;
#pragma unroll
      for (int k = 0; k < 4; ++k) A0.u[k] = cvtpk(p[2 * k], p[2 * k + 1]);
#pragma unroll
      for (int k = 0; k < 4; ++k) A1.u[k] = cvtpk(p[8 + 2 * k], p[9 + 2 * k]);

      const char* Vb = (const char*)&Vl[buf][0] + vread;
      __builtin_amdgcn_s_setprio(1);
#pragma unroll
      for (int ct = 0; ct < 8; ++ct) {
        bf16x8 vf0 = *(const bf16x8*)(Vb + ct * 512);
        o[ct] = __builtin_amdgcn_mfma_f32_32x32x16_bf16(A0.v8, vf0, o[ct], 0, 0, 0);
        bf16x8 vf1 = *(const bf16x8*)(Vb + 8192 + ct * 512);
        o[ct] = __builtin_amdgcn_mfma_f32_32x32x16_bf16(A1.v8, vf1, o[ct], 0, 0, 0);
      }
      __builtin_amdgcn_s_setprio(0);
    }
    if (nl) MLOAD(t0 + tt + 1);
    __builtin_amdgcn_s_barrier();
  }

  if (valid) {
    float lt = lsum + __shfl_xor(lsum, 32);
#pragma unroll
    for (int r = 0; r < 16; ++r) {
      int q = (r & 3) + 8 * (r >> 2) + 4 * hi;
      int qt16 = qu * 2 + (q >> 4);
      int row = q & 15;
      size_t ob = ((((size_t)b * QT_ + qt16) * CH_ + chunk) * 2048) + row * 128 + cl;
#pragma unroll
      for (int pp = 0; pp < 4; ++pp)
        pOb[ob + pp * 32] = cvtpk(o[2 * pp][r], o[2 * pp + 1][r]);
    }
    if (lane < 32) {
      int qt16 = qu * 2 + (cl >> 4);
      int row = cl & 15;
      float* pml = pML + (((size_t)b * QT_ + qt16) * CH_ + chunk) * 32;
      pml[row] = FMAX_;
      pml[16 + row] = lt;
    }
  }
}

// ======== out_linear block body (r13, exact; bid-decomposed) ========
__device__ __forceinline__ void out_linear_body(
    int bid,
    const __hip_bfloat16* __restrict__ refb, const __hip_bfloat16* __restrict__ fb,
    const __hip_bfloat16* __restrict__ Wl, const float* __restrict__ bl,
    float* __restrict__ out)
{
  const int b    = bid / 196;
  const int rest = bid % 196;
  const int cblk = rest / 98;
  const int nblk = rest % 98;
  const int wave = threadIdx.x >> 6;
  const int lane = threadIdx.x & 63;
  const int qt = lane & 15, g = lane >> 4;
  const int c0 = cblk * 128 + wave * 32;
  const int n0 = nblk * 32;
  const __hip_bfloat16* rb  = refb + (size_t)b * N_ * C_;
  const __hip_bfloat16* fbb = fb  + (size_t)b * N_ * C_;
  f32x4 acc[2][2];
#pragma unroll
  for (int u = 0; u < 2; ++u)
#pragma unroll
    for (int j = 0; j < 2; ++j) acc[u][j] = (f32x4){0.f, 0.f, 0.f, 0.f};
#pragma unroll
  for (int kk = 0; kk < 16; ++kk) {
    int ko2 = (kk * 32 + g * 8) & 255;
    const __hip_bfloat16* src = (kk < 8) ? rb : fbb;
    bf16x8 bb0 = *(const bf16x8*)(src + (size_t)(n0 + qt) * C_ + ko2);
    bf16x8 bb1 = *(const bf16x8*)(src + (size_t)(n0 + 16 + qt) * C_ + ko2);
#pragma unroll
    for (int u = 0; u < 2; ++u) {
      int ct = cblk * 8 + wave * 2 + u;
      bf16x8 a = *(const bf16x8*)(Wl + (size_t)((ct * 16 + kk) * 64 + lane) * 8);
      acc[u][0] = __builtin_amdgcn_mfma_f32_16x16x32_bf16(a, bb0, acc[u][0], 0, 0, 0);
      acc[u][1] = __builtin_amdgcn_mfma_f32_16x16x32_bf16(a, bb1, acc[u][1], 0, 0, 0);
    }
  }
  float* ob = out + (size_t)b * 4 * C_ * N_;
#pragma unroll
  for (int u = 0; u < 2; ++u)
#pragma unroll
    for (int j = 0; j < 2; ++j)
#pragma unroll
      for (int r = 0; r < 4; ++r) {
        int c = c0 + u * 16 + 4 * g + r;
        int n = n0 + j * 16 + qt;
        ob[(size_t)c * N_ + n] = acc[u][j][r] + bl[c];
      }
}

// ---- standalone attn (stage 0) ----
__global__ __launch_bounds__(256, 2) void attn_kernel(
    const __hip_bfloat16* __restrict__ qb, const __hip_bfloat16* __restrict__ kb,
    const __hip_bfloat16* __restrict__ vT, const __hip_bfloat16* __restrict__ mb,
    unsigned* __restrict__ pOb, float* __restrict__ pML)
{
  attn_body(blockIdx.x, qb, kb, vT, mb, pOb, pML);
}

// ---- fused: attn(s) [bid<500] + out_linear(s-1) [bid>=500] ----
__global__ __launch_bounds__(256, 2) void attn_out_kernel(
    const __hip_bfloat16* __restrict__ qb, const __hip_bfloat16* __restrict__ kb,
    const __hip_bfloat16* __restrict__ vT, const __hip_bfloat16* __restrict__ mb,
    unsigned* __restrict__ pOb, float* __restrict__ pML,
    const __hip_bfloat16* __restrict__ refb, const __hip_bfloat16* __restrict__ fprev,
    const __hip_bfloat16* __restrict__ Wl, const float* __restrict__ bl,
    float* __restrict__ outp)
{
  if (blockIdx.x < 500)
    attn_body(blockIdx.x, qb, kb, vT, mb, pOb, pML);
  else
    out_linear_body(blockIdx.x - 500, refb, fprev, Wl, bl, outp);
}

// ---- standalone out_linear (final stage) ----
__global__ __launch_bounds__(256) void out_linear_kernel(
    const __hip_bfloat16* __restrict__ refb,
    const __hip_bfloat16* __restrict__ fb,
    const __hip_bfloat16* __restrict__ Wl,
    const float* __restrict__ bl,
    float* __restrict__ out)
{
  out_linear_body(blockIdx.x, refb, fb, Wl, bl, out);
}

// ---- combine CH partials (coalesced): thread t <-> word w = t&127 of rows t>>7 ----
__global__ __launch_bounds__(256) void combine_kernel(
    const unsigned* __restrict__ pOb, const float* __restrict__ pML,
    const __hip_bfloat16* __restrict__ fb,
    __hip_bfloat16* __restrict__ ref)
{
  __shared__ float sml[CH_ * 32];
  const int b = blockIdx.y;
  const int qtile = blockIdx.x;
  const int tid = threadIdx.x;
  const float* pml = pML + ((size_t)b * QT_ + qtile) * (CH_ * 32);
  if (tid < CH_ * 32) sml[tid] = pml[tid];
  __syncthreads();

  const int w  = tid & 127;
  const int r0 = (tid >> 7) * 8;
  const int ch_lo = 64 * (w >> 5) + (w & 31);
  const int ch_hi = ch_lo + 32;

  float wgt[CH_][8];
#pragma unroll
  for (int r = 0; r < 8; ++r) {
    int row = r0 + r;
    float M = sml[row];
#pragma unroll
    for (int ch = 1; ch < CH_; ++ch) M = fmaxf(M, sml[ch * 32 + row]);
    float L = 0.f;
#pragma unroll
    for (int ch = 0; ch < CH_; ++ch) {
      float wv = exp2f(sml[ch * 32 + row] - M);
      wgt[ch][r] = wv;
      L += wv * sml[ch * 32 + 16 + row];
    }
    float iL = 1.f / L;
#pragma unroll
    for (int ch = 0; ch < CH_; ++ch) wgt[ch][r] *= iL;
  }

  float acc_lo[8], acc_hi[8];
#pragma unroll
  for (int r = 0; r < 8; ++r) { acc_lo[r] = 0.f; acc_hi[r] = 0.f; }
  const unsigned* base = pOb + ((size_t)b * QT_ + qtile) * (CH_ * 2048) + r0 * 128 + w;
#pragma unroll
  for (int ch = 0; ch < CH_; ++ch) {
    const unsigned* p = base + ch * 2048;
#pragma unroll
    for (int r = 0; r < 8; ++r) {
      unsigned u = p[r * 128];
      acc_lo[r] += wgt[ch][r] * __uint_as_float(u << 16);
      acc_hi[r] += wgt[ch][r] * __uint_as_float(u & 0xffff0000u);
    }
  }

  const __hip_bfloat16* f = fb + ((size_t)b * N_ + qtile * 16 + r0) * C_;
  __hip_bfloat16* rf = ref + ((size_t)b * N_ + qtile * 16 + r0) * C_;
#pragma unroll
  for (int r = 0; r < 8; ++r) {
    rf[r * C_ + ch_lo] = __float2bfloat16(acc_lo[r] + __bfloat162float(f[r * C_ + ch_lo]));
    rf[r * C_ + ch_hi] = __float2bfloat16(acc_hi[r] + __bfloat162float(f[r * C_ + ch_hi]));
  }
}

extern "C" void kernel_launch(void* const* d_in, const int* in_sizes, int n_in,
                              void* d_out, int out_size, void* d_ws, size_t ws_size,
                              hipStream_t stream) {
  (void)in_sizes; (void)n_in; (void)out_size; (void)ws_size;
  const float* feat0 = (const float*)d_in[0];
  const float* feat1 = (const float*)d_in[1];
  const float* feat2 = (const float*)d_in[2];
  const float* feat3 = (const float*)d_in[3];
  const float* mask  = (const float*)d_in[7];
  const float* Wv    = (const float*)d_in[8];
  const float* bv    = (const float*)d_in[9];
  const float* Wl    = (const float*)d_in[10];
  const float* bl    = (const float*)d_in[11];
  float* out = (float*)d_out;

  const size_t TOKB = (size_t)B_ * N_ * C_ * 2;  // 6,422,528
  char* w = (char*)d_ws;
  __hip_bfloat16* q0   = (__hip_bfloat16*)(w);
  __hip_bfloat16* f1   = (__hip_bfloat16*)(w + TOKB);
  __hip_bfloat16* f2   = (__hip_bfloat16*)(w + 2 * TOKB);
  __hip_bfloat16* f3   = (__hip_bfloat16*)(w + 3 * TOKB);
  __hip_bfloat16* vT0  = (__hip_bfloat16*)(w + 4 * TOKB);  // -> refined(0), refined(2)
  __hip_bfloat16* vT1  = (__hip_bfloat16*)(w + 5 * TOKB);  // -> refined(1)
  __hip_bfloat16* vT2  = (__hip_bfloat16*)(w + 6 * TOKB);
  char* w2 = w + 7 * TOKB;
  __hip_bfloat16* Wv_bf = (__hip_bfloat16*)(w2);
  __hip_bfloat16* Wl_bf = (__hip_bfloat16*)(w2 + 131072);
  __hip_bfloat16* maskb = (__hip_bfloat16*)(w2 + 393216);
  unsigned* pOb         = (unsigned*)(w2 + 393216 + 19668992);
  float* pML            = (float*)(w2 + 393216 + 19668992 + (size_t)B_ * QT_ * CH_ * 4096 * 2);

  dim3 tb(256);
  transpose4_kernel<<<dim3(98, 8, 16), tb, 0, stream>>>(feat0, feat1, feat2, feat3,
                                                        q0, f1, f2, f3, out);
  cvt_all_kernel<<<dim3((24576 + NKV_ * NKV_ * 64 + 255) / 256), tb, 0, stream>>>(
      Wv, Wl, mask, Wv_bf, Wl_bf, maskb);
  v_linear_kernel<<<dim3(49, 4, 3), tb, 0, stream>>>(f1, f2, f3, Wv_bf, bv,
                                                     vT0, vT1, vT2);

  // stage 0
  attn_kernel<<<dim3(500), tb, 0, stream>>>(q0, f1, vT0, maskb, pOb, pML);
  combine_kernel<<<dim3(196, 4), tb, 0, stream>>>(pOb, pML, f1, vT0);   // refined0 -> vT0
  // stage 1 attn + stage 0 out_linear (both only read refined0)
  attn_out_kernel<<<dim3(1284), tb, 0, stream>>>(vT0, f2, vT1, maskb, pOb, pML,
                                                 vT0, f1, Wl_bf, bl,
                                                 out + (size_t)1 * C_ * N_);
  combine_kernel<<<dim3(196, 4), tb, 0, stream>>>(pOb, pML, f2, vT1);   // refined1 -> vT1
  // stage 2 attn + stage 1 out_linear
  attn_out_kernel<<<dim3(1284), tb, 0, stream>>>(vT1, f3, vT2, maskb, pOb, pML,
                                                 vT1, f2, Wl_bf, bl,
                                                 out + (size_t)2 * C_ * N_);
  combine_kernel<<<dim3(196, 4), tb, 0, stream>>>(pOb, pML, f3, vT0);   // refined2 -> vT0
  out_linear_kernel<<<dim3(784), tb, 0, stream>>>(vT0, f3, Wl_bf, bl,
                                                  out + (size_t)3 * C_ * N_);
}

// Round 17
// 313.363 us; speedup vs baseline: 1.1243x; 1.0160x over previous
//
#include <hip/hip_runtime.h>
#include <hip/hip_bf16.h>

// Problem constants
#define B_   4
#define C_   256
#define N_   3136
#define QT_  196     // N/16 q-tiles per batch
#define NKV_ 98      // N/32 kv tiles
#define CH_  5       // KV chunks (proven r10/r13 config)

typedef __attribute__((ext_vector_type(8)))  short bf16x8;
typedef __attribute__((ext_vector_type(4)))  float f32x4;
typedef __attribute__((ext_vector_type(16))) float f32x16;

#define LOG2E  1.4426950408889634f
#define SCALE2 (LOG2E / 16.0f)     // (1/sqrt(C)) * log2(e)
#define FMAX_  20.0f               // fixed softmax max (log2 domain); logits*log2e < ~12.3

__device__ __forceinline__ unsigned short bfbits(float f) {
  __hip_bfloat16 h = __float2bfloat16(f);
  return *(unsigned short*)&h;
}
__device__ __forceinline__ unsigned cvtpk(float lo, float hi) {
  unsigned r;
  asm("v_cvt_pk_bf16_f32 %0, %1, %2" : "=v"(r) : "v"(lo), "v"(hi));
  return r;
}

// ---- async global->LDS 16B helper (dest must be linear: base + lane*16) ----
__device__ __forceinline__ void gld16(const void* g, void* l) {
  __builtin_amdgcn_global_load_lds(
      (const __attribute__((address_space(1))) unsigned int*)g,
      (__attribute__((address_space(3))) unsigned int*)l, 16, 0, 0);
}

// key-column permutation inside each 32-group (PV zero-exchange layout)
__device__ __forceinline__ int vperm(int n) {
  int k = n & 31;
  return (n & ~31) | (k & 16) | (((k >> 2) & 1) << 3) | (k & 3) | (((k >> 3) & 1) << 2);
}

// ======== prep: transpose4 [bid<12544] + converts [bid>=12544] ========
// transpose: [b][c][n] f32 -> [b][n][c] bf16; feat0 also copied to out slot 0
// cvt: Wv/Wl -> MFMA-fragment-linear bf16; mask -> coalesced per-wave-tile bf16
__global__ __launch_bounds__(256) void prep_kernel(
    const float* __restrict__ f0, const float* __restrict__ f1,
    const float* __restrict__ f2, const float* __restrict__ f3,
    __hip_bfloat16* __restrict__ d0, __hip_bfloat16* __restrict__ d1,
    __hip_bfloat16* __restrict__ d2, __hip_bfloat16* __restrict__ d3,
    float* __restrict__ out,
    const float* __restrict__ Wv, const float* __restrict__ Wl,
    const float* __restrict__ mask,
    __hip_bfloat16* __restrict__ Wvb, __hip_bfloat16* __restrict__ Wlb,
    __hip_bfloat16* __restrict__ maskb)
{
  const int bid = blockIdx.x;
  if (bid < 12544) {
    __shared__ float tile[32][33];
    const int z  = bid / 784;
    const int rest = bid % 784;
    const int fi = z >> 2;
    const int b  = z & 3;
    const float* src = (fi == 0) ? f0 : (fi == 1) ? f1 : (fi == 2) ? f2 : f3;
    __hip_bfloat16* dst = (fi == 0) ? d0 : (fi == 1) ? d1 : (fi == 2) ? d2 : d3;
    const int n0 = (rest % 98) * 32;
    const int c0 = (rest / 98) * 32;
    const int tx = threadIdx.x & 31;
    const int ty = threadIdx.x >> 5;
    const float* s = src + (size_t)b * C_ * N_;
    float* ob = out + (size_t)b * 4 * C_ * N_;
#pragma unroll
    for (int i = 0; i < 4; ++i) {
      int c = c0 + ty + i * 8;
      float v = s[(size_t)c * N_ + n0 + tx];
      tile[ty + i * 8][tx] = v;
      if (fi == 0) ob[(size_t)c * N_ + n0 + tx] = v;
    }
    __syncthreads();
    __hip_bfloat16* d = dst + (size_t)b * N_ * C_;
#pragma unroll
    for (int i = 0; i < 4; ++i) {
      int n = n0 + ty + i * 8;
      d[(size_t)n * C_ + c0 + tx] = __float2bfloat16(tile[tx][ty + i * 8]);
    }
    return;
  }
  int i = (bid - 12544) * 256 + threadIdx.x;
  if (i < 24576) {
    const float* src; __hip_bfloat16* dstp; int off, dst8;
    if (i < 8192) {
      off = i; src = Wv; dstp = Wvb;
      int row = off >> 5, c8 = off & 31;            // K=256: 32 groups/row
      int ct = row >> 4, qt = row & 15, kk = c8 >> 2, g = c8 & 3;
      dst8 = (ct * 8 + kk) * 64 + g * 16 + qt;
    } else {
      off = i - 8192; src = Wl; dstp = Wlb;
      int row = off >> 6, c8 = off & 63;            // K=512: 64 groups/row
      int ct = row >> 4, qt = row & 15, kk = c8 >> 2, g = c8 & 3;
      dst8 = (ct * 16 + kk) * 64 + g * 16 + qt;
    }
    const float4* s4 = (const float4*)src;
    float4 a = s4[2 * off], b = s4[2 * off + 1];
    union { unsigned short u[8]; bf16x8 v; } p;
    p.u[0]=bfbits(a.x); p.u[1]=bfbits(a.y); p.u[2]=bfbits(a.z); p.u[3]=bfbits(a.w);
    p.u[4]=bfbits(b.x); p.u[5]=bfbits(b.y); p.u[6]=bfbits(b.z); p.u[7]=bfbits(b.w);
    *(bf16x8*)(dstp + 8 * dst8) = p.v;
    return;
  }
  int j = i - 24576;
  if (j >= NKV_ * NKV_ * 32 * 2) return;   // 98*98*32*2
  const int hi  = j & 1;
  const int cl  = (j >> 1) & 31;
  const int rem = j >> 6;          // qu*98 + kt
  const int kt  = rem % NKV_;
  const int qu  = rem / NKV_;
  const int q   = qu * 32 + cl;
  const float* s = mask + (size_t)q * N_ + kt * 32 + 4 * hi;
  float4 a0 = *(const float4*)(s);
  float4 a1 = *(const float4*)(s + 8);
  float4 a2 = *(const float4*)(s + 16);
  float4 a3 = *(const float4*)(s + 24);
  union { unsigned short u[16]; bf16x8 v[2]; } p;
  p.u[0]=bfbits(a0.x*LOG2E); p.u[1]=bfbits(a0.y*LOG2E); p.u[2]=bfbits(a0.z*LOG2E); p.u[3]=bfbits(a0.w*LOG2E);
  p.u[4]=bfbits(a1.x*LOG2E); p.u[5]=bfbits(a1.y*LOG2E); p.u[6]=bfbits(a1.z*LOG2E); p.u[7]=bfbits(a1.w*LOG2E);
  p.u[8]=bfbits(a2.x*LOG2E); p.u[9]=bfbits(a2.y*LOG2E); p.u[10]=bfbits(a2.z*LOG2E); p.u[11]=bfbits(a2.w*LOG2E);
  p.u[12]=bfbits(a3.x*LOG2E); p.u[13]=bfbits(a3.y*LOG2E); p.u[14]=bfbits(a3.z*LOG2E); p.u[15]=bfbits(a3.w*LOG2E);
  __hip_bfloat16* d = maskb + ((size_t)rem * 32 + cl) * 32 + hi * 16;
  *(bf16x8*)(d)     = p.v[0];
  *(bf16x8*)(d + 8) = p.v[1];
}

// ======== v_linear block body ========
__device__ __forceinline__ void vlin_body(
    int nblk, int b,
    const __hip_bfloat16* __restrict__ fb,
    const __hip_bfloat16* __restrict__ Wv,   // fragment-linear
    const float* __restrict__ bv,
    __hip_bfloat16* __restrict__ vT)
{
  const int wave = threadIdx.x >> 6;
  const int lane = threadIdx.x & 63;
  const int qt = lane & 15, g = lane >> 4;
  const int n0 = nblk * 64;
  const __hip_bfloat16* fbb = fb + (size_t)b * N_ * C_;
  const int c0 = wave * 64;
  f32x4 acc[4][4];
#pragma unroll
  for (int u = 0; u < 4; ++u)
#pragma unroll
    for (int j = 0; j < 4; ++j) acc[u][j] = (f32x4){0.f, 0.f, 0.f, 0.f};
#pragma unroll
  for (int kk = 0; kk < 8; ++kk) {
    int ko = kk * 32 + g * 8;
    bf16x8 bb[4];
#pragma unroll
    for (int j = 0; j < 4; ++j)
      bb[j] = *(const bf16x8*)(fbb + (size_t)(n0 + j * 16 + qt) * C_ + ko);
#pragma unroll
    for (int u = 0; u < 4; ++u) {
      bf16x8 a = *(const bf16x8*)(Wv + (size_t)(((wave * 4 + u) * 8 + kk) * 64 + lane) * 8);
#pragma unroll
      for (int j = 0; j < 4; ++j)
        acc[u][j] = __builtin_amdgcn_mfma_f32_16x16x32_bf16(a, bb[j], acc[u][j], 0, 0, 0);
    }
  }
  __hip_bfloat16* outp = vT + (size_t)b * C_ * N_;
#pragma unroll
  for (int u = 0; u < 4; ++u)
#pragma unroll
    for (int j = 0; j < 4; ++j)
#pragma unroll
      for (int r = 0; r < 4; ++r) {
        int c = c0 + u * 16 + 4 * g + r;
        int n = vperm(n0 + j * 16 + qt);
        outp[(size_t)c * N_ + n] = __float2bfloat16(acc[u][j][r] + bv[c]);
      }
}

// ---- standalone v_linear (stage 0 only): grid (49, 4) ----
__global__ __launch_bounds__(256) void v_linear_kernel(
    const __hip_bfloat16* __restrict__ fb,
    const __hip_bfloat16* __restrict__ Wv, const float* __restrict__ bv,
    __hip_bfloat16* __restrict__ vT)
{
  vlin_body(blockIdx.x, blockIdx.y, fb, Wv, bv, vT);
}

// ======== attn block body (r13, exact) ========
__device__ __forceinline__ void attn_body(
    int bid,
    const __hip_bfloat16* __restrict__ qb, const __hip_bfloat16* __restrict__ kb,
    const __hip_bfloat16* __restrict__ vT, const __hip_bfloat16* __restrict__ mb,
    unsigned* __restrict__ pOb, float* __restrict__ pML)
{
  __shared__ __hip_bfloat16 Kl[2][32 * 256];   // 2 x 16KB
  __shared__ __hip_bfloat16 Vl[2][32 * 256];   // 2 x 16KB

  const int grp   = bid % 20;
  const int qblk  = bid / 20;         // 0..24
  const int b     = grp / CH_;
  const int chunk = grp % CH_;
  const int wave  = threadIdx.x >> 6;
  const int lane  = threadIdx.x & 63;
  const int cl = lane & 31, hi = lane >> 5;
  const int qunit = qblk * 4 + wave;           // 32-row q unit
  const bool valid = qunit < 98;
  const int qu = valid ? qunit : 97;
  const int q0row = qu * 32 + cl;
  const int t0 = (chunk * NKV_) / CH_;
  const int t1 = ((chunk + 1) * NKV_) / CH_;
  const int nt = t1 - t0;
  const int tid = threadIdx.x;

  const __hip_bfloat16* qbb = qb + (size_t)b * N_ * C_;
  const char* kbbc = (const char*)(kb + (size_t)b * N_ * C_);
  const char* vbbc = (const char*)(vT + (size_t)b * C_ * N_);
  const char* mbase = (const char*)mb + (size_t)qu * (NKV_ * 2048) + cl * 64 + hi * 32;

  bf16x8 qa[16];
#pragma unroll
  for (int ks = 0; ks < 16; ++ks)
    qa[ks] = *(const bf16x8*)(qbb + (size_t)q0row * C_ + ks * 16 + 8 * hi);

  f32x16 o[8];
#pragma unroll
  for (int ct = 0; ct < 8; ++ct)
#pragma unroll
    for (int r = 0; r < 16; ++r) o[ct][r] = 0.f;
  float lsum = 0.f;

  auto STAGE = [&](int buf, int t) {
    const char* ks0 = kbbc + (size_t)t * 32 * 512;
#pragma unroll
    for (int i = 0; i < 4; ++i) {
      int g2 = tid + i * 256;
      int ks = g2 >> 6, h2 = (g2 >> 5) & 1, key = g2 & 31;
      gld16(ks0 + key * 512 + ks * 32 + h2 * 16, (char*)&Kl[buf][0] + g2 * 16);
    }
    const char* vs0 = vbbc + (size_t)t * 64;
#pragma unroll
    for (int i = 0; i < 4; ++i) {
      int g2 = tid + i * 256;
      int st = g2 >> 9, h2 = (g2 >> 8) & 1, c = g2 & 255;
      gld16(vs0 + (size_t)c * (N_ * 2) + st * 32 + h2 * 16, (char*)&Vl[buf][0] + g2 * 16);
    }
  };

  union { uint4 v[2]; unsigned w[8]; } mm;
  auto MLOAD = [&](int t) {
    mm.v[0] = *(const uint4*)(mbase + (size_t)t * 2048);
    mm.v[1] = *(const uint4*)(mbase + (size_t)t * 2048 + 16);
  };

  STAGE(0, t0);
  MLOAD(t0);

  const int kread = hi * 512 + cl * 16;
  const int vread = hi * 4096 + cl * 16;

  for (int tt = 0; tt < nt; ++tt) {
    const int buf = tt & 1;
    const bool nl = (tt + 1 < nt);
    if (nl) STAGE(buf ^ 1, t0 + tt + 1);
    if (nl) asm volatile("s_waitcnt vmcnt(10)" ::: "memory");
    else    asm volatile("s_waitcnt vmcnt(2)"  ::: "memory");
    __builtin_amdgcn_s_barrier();

    f32x16 s;
#pragma unroll
    for (int r = 0; r < 16; ++r) s[r] = 0.f;
    if (valid) {
      const char* Kb = (const char*)&Kl[buf][0] + kread;
      __builtin_amdgcn_s_setprio(1);
#pragma unroll
      for (int ks = 0; ks < 16; ++ks) {
        bf16x8 kf = *(const bf16x8*)(Kb + ks * 1024);
        s = __builtin_amdgcn_mfma_f32_32x32x16_bf16(kf, qa[ks], s, 0, 0, 0);
      }
      __builtin_amdgcn_s_setprio(0);
    }

    if (valid) {
      float p[16];
#pragma unroll
      for (int j = 0; j < 16; ++j) {
        unsigned wo = mm.w[j >> 1];
        float mf = __uint_as_float((j & 1) ? (wo & 0xffff0000u) : (wo << 16));
        p[j] = exp2f(fmaf(s[j], SCALE2, mf) - FMAX_);
      }
      lsum += ((p[0]+p[1])+(p[2]+p[3])) + ((p[4]+p[5])+(p[6]+p[7]))
            + ((p[8]+p[9])+(p[10]+p[11])) + ((p[12]+p[13])+(p[14]+p[15]));

      union { unsigned u[4]; bf16x8 v8; } A0, A1;
#pragma unroll
      for (int k = 0; k < 4; ++k) A0.u[k] = cvtpk(p[2 * k], p[2 * k + 1]);
#pragma unroll
      for (int k = 0; k < 4; ++k) A1.u[k] = cvtpk(p[8 + 2 * k], p[9 + 2 * k]);

      const char* Vb = (const char*)&Vl[buf][0] + vread;
      __builtin_amdgcn_s_setprio(1);
#pragma unroll
      for (int ct = 0; ct < 8; ++ct) {
        bf16x8 vf0 = *(const bf16x8*)(Vb + ct * 512);
        o[ct] = __builtin_amdgcn_mfma_f32_32x32x16_bf16(A0.v8, vf0, o[ct], 0, 0, 0);
        bf16x8 vf1 = *(const bf16x8*)(Vb + 8192 + ct * 512);
        o[ct] = __builtin_amdgcn_mfma_f32_32x32x16_bf16(A1.v8, vf1, o[ct], 0, 0, 0);
      }
      __builtin_amdgcn_s_setprio(0);
    }
    if (nl) MLOAD(t0 + tt + 1);
    __builtin_amdgcn_s_barrier();
  }

  if (valid) {
    float lt = lsum + __shfl_xor(lsum, 32);
#pragma unroll
    for (int r = 0; r < 16; ++r) {
      int q = (r & 3) + 8 * (r >> 2) + 4 * hi;
      int qt16 = qu * 2 + (q >> 4);
      int row = q & 15;
      size_t ob = ((((size_t)b * QT_ + qt16) * CH_ + chunk) * 2048) + row * 128 + cl;
#pragma unroll
      for (int pp = 0; pp < 4; ++pp)
        pOb[ob + pp * 32] = cvtpk(o[2 * pp][r], o[2 * pp + 1][r]);
    }
    if (lane < 32) {
      int qt16 = qu * 2 + (cl >> 4);
      int row = cl & 15;
      float* pml = pML + (((size_t)b * QT_ + qt16) * CH_ + chunk) * 32;
      pml[row] = FMAX_;
      pml[16 + row] = lt;
    }
  }
}

// ======== out_linear block body (r13, exact; bid-decomposed) ========
__device__ __forceinline__ void out_linear_body(
    int bid,
    const __hip_bfloat16* __restrict__ refb, const __hip_bfloat16* __restrict__ fb,
    const __hip_bfloat16* __restrict__ Wl, const float* __restrict__ bl,
    float* __restrict__ out)
{
  const int b    = bid / 196;
  const int rest = bid % 196;
  const int cblk = rest / 98;
  const int nblk = rest % 98;
  const int wave = threadIdx.x >> 6;
  const int lane = threadIdx.x & 63;
  const int qt = lane & 15, g = lane >> 4;
  const int c0 = cblk * 128 + wave * 32;
  const int n0 = nblk * 32;
  const __hip_bfloat16* rb  = refb + (size_t)b * N_ * C_;
  const __hip_bfloat16* fbb = fb  + (size_t)b * N_ * C_;
  f32x4 acc[2][2];
#pragma unroll
  for (int u = 0; u < 2; ++u)
#pragma unroll
    for (int j = 0; j < 2; ++j) acc[u][j] = (f32x4){0.f, 0.f, 0.f, 0.f};
#pragma unroll
  for (int kk = 0; kk < 16; ++kk) {
    int ko2 = (kk * 32 + g * 8) & 255;
    const __hip_bfloat16* src = (kk < 8) ? rb : fbb;
    bf16x8 bb0 = *(const bf16x8*)(src + (size_t)(n0 + qt) * C_ + ko2);
    bf16x8 bb1 = *(const bf16x8*)(src + (size_t)(n0 + 16 + qt) * C_ + ko2);
#pragma unroll
    for (int u = 0; u < 2; ++u) {
      int ct = cblk * 8 + wave * 2 + u;
      bf16x8 a = *(const bf16x8*)(Wl + (size_t)((ct * 16 + kk) * 64 + lane) * 8);
      acc[u][0] = __builtin_amdgcn_mfma_f32_16x16x32_bf16(a, bb0, acc[u][0], 0, 0, 0);
      acc[u][1] = __builtin_amdgcn_mfma_f32_16x16x32_bf16(a, bb1, acc[u][1], 0, 0, 0);
    }
  }
  float* ob = out + (size_t)b * 4 * C_ * N_;
#pragma unroll
  for (int u = 0; u < 2; ++u)
#pragma unroll
    for (int j = 0; j < 2; ++j)
#pragma unroll
      for (int r = 0; r < 4; ++r) {
        int c = c0 + u * 16 + 4 * g + r;
        int n = n0 + j * 16 + qt;
        ob[(size_t)c * N_ + n] = acc[u][j][r] + bl[c];
      }
}

// ---- fused: attn stage 0 [bid<500] + v_linear stages 1,2 [bid>=500] ----
__global__ __launch_bounds__(256, 2) void attn_vlin_kernel(
    const __hip_bfloat16* __restrict__ qb, const __hip_bfloat16* __restrict__ kb,
    const __hip_bfloat16* __restrict__ vT, const __hip_bfloat16* __restrict__ mb,
    unsigned* __restrict__ pOb, float* __restrict__ pML,
    const __hip_bfloat16* __restrict__ f2, const __hip_bfloat16* __restrict__ f3,
    const __hip_bfloat16* __restrict__ Wv, const float* __restrict__ bv,
    __hip_bfloat16* __restrict__ vT1, __hip_bfloat16* __restrict__ vT2)
{
  if (blockIdx.x < 500) {
    attn_body(blockIdx.x, qb, kb, vT, mb, pOb, pML);
  } else {
    int v = blockIdx.x - 500;          // 0..391
    int s = v / 196;                   // 0 -> stage1, 1 -> stage2
    int rest = v % 196;
    vlin_body(rest % 49, rest / 49, s ? f3 : f2, Wv, bv, s ? vT2 : vT1);
  }
}

// ---- fused: attn(s) [bid<500] + out_linear(s-1) [bid>=500] ----
__global__ __launch_bounds__(256, 2) void attn_out_kernel(
    const __hip_bfloat16* __restrict__ qb, const __hip_bfloat16* __restrict__ kb,
    const __hip_bfloat16* __restrict__ vT, const __hip_bfloat16* __restrict__ mb,
    unsigned* __restrict__ pOb, float* __restrict__ pML,
    const __hip_bfloat16* __restrict__ refb, const __hip_bfloat16* __restrict__ fprev,
    const __hip_bfloat16* __restrict__ Wl, const float* __restrict__ bl,
    float* __restrict__ outp)
{
  if (blockIdx.x < 500)
    attn_body(blockIdx.x, qb, kb, vT, mb, pOb, pML);
  else
    out_linear_body(blockIdx.x - 500, refb, fprev, Wl, bl, outp);
}

// ---- standalone out_linear (final stage) ----
__global__ __launch_bounds__(256) void out_linear_kernel(
    const __hip_bfloat16* __restrict__ refb,
    const __hip_bfloat16* __restrict__ fb,
    const __hip_bfloat16* __restrict__ Wl,
    const float* __restrict__ bl,
    float* __restrict__ out)
{
  out_linear_body(blockIdx.x, refb, fb, Wl, bl, out);
}

// ---- combine CH partials (coalesced): thread t <-> word w = t&127 of rows t>>7 ----
__global__ __launch_bounds__(256) void combine_kernel(
    const unsigned* __restrict__ pOb, const float* __restrict__ pML,
    const __hip_bfloat16* __restrict__ fb,
    __hip_bfloat16* __restrict__ ref)
{
  __shared__ float sml[CH_ * 32];
  const int b = blockIdx.y;
  const int qtile = blockIdx.x;
  const int tid = threadIdx.x;
  const float* pml = pML + ((size_t)b * QT_ + qtile) * (CH_ * 32);
  if (tid < CH_ * 32) sml[tid] = pml[tid];
  __syncthreads();

  const int w  = tid & 127;
  const int r0 = (tid >> 7) * 8;
  const int ch_lo = 64 * (w >> 5) + (w & 31);
  const int ch_hi = ch_lo + 32;

  float wgt[CH_][8];
#pragma unroll
  for (int r = 0; r < 8; ++r) {
    int row = r0 + r;
    float M = sml[row];
#pragma unroll
    for (int ch = 1; ch < CH_; ++ch) M = fmaxf(M, sml[ch * 32 + row]);
    float L = 0.f;
#pragma unroll
    for (int ch = 0; ch < CH_; ++ch) {
      float wv = exp2f(sml[ch * 32 + row] - M);
      wgt[ch][r] = wv;
      L += wv * sml[ch * 32 + 16 + row];
    }
    float iL = 1.f / L;
#pragma unroll
    for (int ch = 0; ch < CH_; ++ch) wgt[ch][r] *= iL;
  }

  float acc_lo[8], acc_hi[8];
#pragma unroll
  for (int r = 0; r < 8; ++r) { acc_lo[r] = 0.f; acc_hi[r] = 0.f; }
  const unsigned* base = pOb + ((size_t)b * QT_ + qtile) * (CH_ * 2048) + r0 * 128 + w;
#pragma unroll
  for (int ch = 0; ch < CH_; ++ch) {
    const unsigned* p = base + ch * 2048;
#pragma unroll
    for (int r = 0; r < 8; ++r) {
      unsigned u = p[r * 128];
      acc_lo[r] += wgt[ch][r] * __uint_as_float(u << 16);
      acc_hi[r] += wgt[ch][r] * __uint_as_float(u & 0xffff0000u);
    }
  }

  const __hip_bfloat16* f = fb + ((size_t)b * N_ + qtile * 16 + r0) * C_;
  __hip_bfloat16* rf = ref + ((size_t)b * N_ + qtile * 16 + r0) * C_;
#pragma unroll
  for (int r = 0; r < 8; ++r) {
    rf[r * C_ + ch_lo] = __float2bfloat16(acc_lo[r] + __bfloat162float(f[r * C_ + ch_lo]));
    rf[r * C_ + ch_hi] = __float2bfloat16(acc_hi[r] + __bfloat162float(f[r * C_ + ch_hi]));
  }
}

extern "C" void kernel_launch(void* const* d_in, const int* in_sizes, int n_in,
                              void* d_out, int out_size, void* d_ws, size_t ws_size,
                              hipStream_t stream) {
  (void)in_sizes; (void)n_in; (void)out_size; (void)ws_size;
  const float* feat0 = (const float*)d_in[0];
  const float* feat1 = (const float*)d_in[1];
  const float* feat2 = (const float*)d_in[2];
  const float* feat3 = (const float*)d_in[3];
  const float* mask  = (const float*)d_in[7];
  const float* Wv    = (const float*)d_in[8];
  const float* bv    = (const float*)d_in[9];
  const float* Wl    = (const float*)d_in[10];
  const float* bl    = (const float*)d_in[11];
  float* out = (float*)d_out;

  const size_t TOKB = (size_t)B_ * N_ * C_ * 2;  // 6,422,528
  char* w = (char*)d_ws;
  __hip_bfloat16* q0   = (__hip_bfloat16*)(w);
  __hip_bfloat16* f1   = (__hip_bfloat16*)(w + TOKB);
  __hip_bfloat16* f2   = (__hip_bfloat16*)(w + 2 * TOKB);
  __hip_bfloat16* f3   = (__hip_bfloat16*)(w + 3 * TOKB);
  __hip_bfloat16* vT0  = (__hip_bfloat16*)(w + 4 * TOKB);  // -> refined(0), refined(2)
  __hip_bfloat16* vT1  = (__hip_bfloat16*)(w + 5 * TOKB);  // -> refined(1)
  __hip_bfloat16* vT2  = (__hip_bfloat16*)(w + 6 * TOKB);
  char* w2 = w + 7 * TOKB;
  __hip_bfloat16* Wv_bf = (__hip_bfloat16*)(w2);
  __hip_bfloat16* Wl_bf = (__hip_bfloat16*)(w2 + 131072);
  __hip_bfloat16* maskb = (__hip_bfloat16*)(w2 + 393216);
  unsigned* pOb         = (unsigned*)(w2 + 393216 + 19668992);
  float* pML            = (float*)(w2 + 393216 + 19668992 + (size_t)B_ * QT_ * CH_ * 4096 * 2);

  dim3 tb(256);
  const int cvtBlocks = (24576 + NKV_ * NKV_ * 64 + 255) / 256;
  prep_kernel<<<dim3(12544 + cvtBlocks), tb, 0, stream>>>(
      feat0, feat1, feat2, feat3, q0, f1, f2, f3, out,
      Wv, Wl, mask, Wv_bf, Wl_bf, maskb);
  v_linear_kernel<<<dim3(49, 4), tb, 0, stream>>>(f1, Wv_bf, bv, vT0);

  // stage 0 attn + v_linear stages 1,2
  attn_vlin_kernel<<<dim3(892), tb, 0, stream>>>(q0, f1, vT0, maskb, pOb, pML,
                                                 f2, f3, Wv_bf, bv, vT1, vT2);
  combine_kernel<<<dim3(196, 4), tb, 0, stream>>>(pOb, pML, f1, vT0);   // refined0 -> vT0
  // stage 1 attn + stage 0 out_linear (both only read refined0)
  attn_out_kernel<<<dim3(1284), tb, 0, stream>>>(vT0, f2, vT1, maskb, pOb, pML,
                                                 vT0, f1, Wl_bf, bl,
                                                 out + (size_t)1 * C_ * N_);
  combine_kernel<<<dim3(196, 4), tb, 0, stream>>>(pOb, pML, f2, vT1);   // refined1 -> vT1
  // stage 2 attn + stage 1 out_linear
  attn_out_kernel<<<dim3(1284), tb, 0, stream>>>(vT1, f3, vT2, maskb, pOb, pML,
                                                 vT1, f2, Wl_bf, bl,
                                                 out + (size_t)2 * C_ * N_);
  combine_kernel<<<dim3(196, 4), tb, 0, stream>>>(pOb, pML, f3, vT0);   // refined2 -> vT0
  out_linear_kernel<<<dim3(784), tb, 0, stream>>>(vT0, f3, Wl_bf, bl,
                                                  out + (size_t)3 * C_ * N_);
}